// Round 13
// baseline (2109.080 us; speedup 1.0000x reference)
//
#include <hip/hip_runtime.h>
#include <cstdint>
#include <cstddef>

#define NN 16384
#define IND 1024
#define HD 256
#define KNN 5
#define NQ 4        // j quarters
#define NCQ 8       // candidates kept per quarter
#define NC2 32      // total candidates per row
#define RPAN 256    // i-rows per panel

typedef __attribute__((ext_vector_type(4))) float f32x4;
typedef __attribute__((ext_vector_type(8))) short bf16x8;

// ===================== GEMM: C = op(A@B [+bias][*rowscale[m]]) =====================
// 64x128 tile, 4x8 micro, 256 threads. A:MxK row-major, B:KxN row-major.
template<bool RELU, bool BIAS, bool RS>
__global__ __launch_bounds__(256) void gemm_4x8(
    const float* __restrict__ A, const float* __restrict__ B,
    const float* __restrict__ bias, const float* __restrict__ rowscale,
    float* __restrict__ C, int M, int Nc, int K)
{
  __shared__ float As[16][68];
  __shared__ float Bs[16][132];
  const int tid = threadIdx.x;
  const int tx = tid & 15, ty = tid >> 4;
  const int m0 = blockIdx.x * 64, n0 = blockIdx.y * 128;

  float acc[4][8];
  #pragma unroll
  for (int i = 0; i < 4; ++i)
    #pragma unroll
    for (int j = 0; j < 8; ++j) acc[i][j] = 0.0f;

  const int am  = tid >> 2;
  const int akq = (tid & 3) * 4;

  for (int kb = 0; kb < K; kb += 16) {
    {
      float4 v = *(const float4*)&A[(size_t)(m0 + am) * K + kb + akq];
      As[akq + 0][am] = v.x; As[akq + 1][am] = v.y;
      As[akq + 2][am] = v.z; As[akq + 3][am] = v.w;
    }
    #pragma unroll
    for (int c = 0; c < 2; ++c) {
      int idx = tid + c * 256;
      int k = idx >> 5;
      int f = idx & 31;
      float4 v = *(const float4*)&B[(size_t)(kb + k) * Nc + n0 + f * 4];
      *(float4*)&Bs[k][f * 4] = v;
    }
    __syncthreads();
    #pragma unroll
    for (int k = 0; k < 16; ++k) {
      float a[4], b[8];
      *(float4*)&a[0] = *(const float4*)&As[k][ty * 4];
      *(float4*)&b[0] = *(const float4*)&Bs[k][tx * 4];
      *(float4*)&b[4] = *(const float4*)&Bs[k][64 + tx * 4];
      #pragma unroll
      for (int i = 0; i < 4; ++i)
        #pragma unroll
        for (int j = 0; j < 8; ++j)
          acc[i][j] = fmaf(a[i], b[j], acc[i][j]);
    }
    __syncthreads();
  }

  float bvals[8];
  if (BIAS) {
    *(float4*)&bvals[0] = *(const float4*)&bias[n0 + tx * 4];
    *(float4*)&bvals[4] = *(const float4*)&bias[n0 + 64 + tx * 4];
  }
  #pragma unroll
  for (int i = 0; i < 4; ++i) {
    int m = m0 + ty * 4 + i;
    float rs = RS ? rowscale[m] : 1.0f;
    float o[8];
    #pragma unroll
    for (int j = 0; j < 8; ++j) {
      float v = acc[i][j];
      if (BIAS) v += bvals[j];
      if (RS) v *= rs;
      if (RELU) v = fmaxf(v, 0.0f);
      o[j] = v;
    }
    *(float4*)&C[(size_t)m * Nc + n0 + tx * 4]      = *(float4*)&o[0];
    *(float4*)&C[(size_t)m * Nc + n0 + 64 + tx * 4] = *(float4*)&o[4];
  }
}

// ===================== fp32 -> bf16 helpers =====================
__device__ __forceinline__ ushort f2bf(float f) {
  uint32_t u = __float_as_uint(f);
  uint32_t r = (u + 0x7fffu + ((u >> 16) & 1u)) >> 16;
  return (ushort)r;
}

// ===================== fused row-norms + bf16 cast (one pass over h) ==========
__global__ __launch_bounds__(256) void sq_split_kernel(
    const float* __restrict__ h, float* __restrict__ sq, ushort* __restrict__ hhi)
{
  const int w = threadIdx.x >> 6, l = threadIdx.x & 63;
  const int r = blockIdx.x * 4 + w;
  float4 v = *(const float4*)&h[(size_t)r * HD + l * 4];
  float s = v.x * v.x + v.y * v.y + v.z * v.z + v.w * v.w;
  #pragma unroll
  for (int o = 32; o; o >>= 1) s += __shfl_down(s, o);
  if (l == 0) sq[r] = s;
  ushort4 H; H.x = f2bf(v.x); H.y = f2bf(v.y); H.z = f2bf(v.z); H.w = f2bf(v.w);
  *(ushort4*)&hhi[(size_t)r * HD + l * 4] = H;
}

// sorted u32-key top-5 insert (k0<k1<...<k4); key embeds index -> unique, and
// for equal distance-bits lower index = lower key.
#define INS5K(v, k) do {                                                \
    if ((k) < v[4]) {                                                   \
      if ((k) < v[0])      { v[4]=v[3];v[3]=v[2];v[2]=v[1];v[1]=v[0];v[0]=(k); } \
      else if ((k) < v[1]) { v[4]=v[3];v[3]=v[2];v[2]=v[1];v[1]=(k); }  \
      else if ((k) < v[2]) { v[4]=v[3];v[3]=v[2];v[2]=(k); }            \
      else if ((k) < v[3]) { v[4]=v[3];v[3]=(k); }                      \
      else                 { v[4]=(k); }                                \
    }                                                                   \
  } while (0)

// ===================== MFMA pairwise-distance -> top-8 candidates per j-quarter ========
// FILTER pass (validated r9-r12, absmax 0.0): 1-term bf16 Gram, key = monotone-u32(d)
// high 18 bits | j (NN=2^14). Exact fp32 rescore recovers the true top-5.
// r12 lesson: L2-miss traffic is the binding resource (dist time ~ FETCH / 2.6TB/s L3
// ceiling); static XCD partitioning cannot stop co-resident blocks drifting out of
// phase. So REDUCE LOGICAL TRAFFIC: panel rows 128->256 halves j-traffic to 537MB
// (worst-case ~205us at L3 BW, with zero cross-block reuse assumed).
// Block: 256 i-rows (bf16 LDS panel 132KB -> 1 block/CU), 512 threads (8 waves,
// 2 waves/SIMD -- r6's proven occupancy). grid = 256 (exactly co-resident, lockstep-
// friendly). quart = bid&3, panel = bid>>2 (atomic XCD claim dropped: r12 no-op).
// j-quarter streamed in 16 chunks of 256 rows; A-operand direct from global, no
// barriers in K-loop, no manual prefetch (r8 spill lesson).
// Lane owns i = fi*16+(lane&15), fi<16; j = wave*32 + fj*16 + (lane>>4)*4 + reg.
// Regs: acc 2x16 f32x4 = 128 AGPR + keys 16x5 = 80 VGPR, fits 256/wave budget.
__global__ __launch_bounds__(512, 2) void dist_topk_mfma(
    const ushort* __restrict__ hhi, const float* __restrict__ sq, int* __restrict__ cand)
{
  // iHi [256][264 us] = 135168 B; merge M (uint, aliases @0): 256 x 40 = 40960 B.
  __shared__ char smem[135168];
  ushort*   iHi = (ushort*)smem;
  uint32_t* M   = (uint32_t*)smem;

  const int tid  = threadIdx.x;
  const int wave = tid >> 6, lane = tid & 63;
  const int l15  = lane & 15, kgrp = lane >> 4;
  const int panel = blockIdx.x >> 2;
  const int quart = blockIdx.x & 3;
  const int rbase = panel * RPAN;
  const int jbeg  = quart * (NN / NQ);

  // ---- stage i-panel (256 x 256 bf16), once: 2 threads/row, 128 us (16 x uint4) each
  {
    const int r = tid >> 1, q = tid & 1;
    const uint4* sH = (const uint4*)&hhi[(size_t)(rbase + r) * HD + q * 128];
    uint4* dH = (uint4*)&iHi[r * 264 + q * 128];
    #pragma unroll
    for (int c = 0; c < 16; ++c) dH[c] = sH[c];
  }
  __syncthreads();

  uint32_t keys[16][5];
  #pragma unroll
  for (int i = 0; i < 16; ++i)
    #pragma unroll
    for (int s = 0; s < 5; ++s) keys[i][s] = 0xFFFFFFFFu;

  for (int j0 = jbeg; j0 < jbeg + NN / NQ; j0 += 256) {
    f32x4 acc0[16], acc1[16];
    #pragma unroll
    for (int fi = 0; fi < 16; ++fi) {
      acc0[fi] = (f32x4){0.f, 0.f, 0.f, 0.f};
      acc1[fi] = (f32x4){0.f, 0.f, 0.f, 0.f};
    }

    #pragma unroll
    for (int kb = 0; kb < 8; ++kb) {
      bf16x8 a0 = *(const bf16x8*)&hhi[(size_t)(j0 + wave * 32 + l15) * HD + kb * 32 + kgrp * 8];
      bf16x8 a1 = *(const bf16x8*)&hhi[(size_t)(j0 + wave * 32 + 16 + l15) * HD + kb * 32 + kgrp * 8];
      #pragma unroll
      for (int fi = 0; fi < 16; ++fi) {
        bf16x8 b = *(const bf16x8*)&iHi[(fi * 16 + l15) * 264 + kb * 32 + kgrp * 8];
        acc0[fi] = __builtin_amdgcn_mfma_f32_16x16x32_bf16(a0, b, acc0[fi], 0, 0, 0);
        acc1[fi] = __builtin_amdgcn_mfma_f32_16x16x32_bf16(a1, b, acc1[fi], 0, 0, 0);
      }
    }

    float4 sqa = *(const float4*)&sq[j0 + wave * 32 + kgrp * 4];
    float4 sqb = *(const float4*)&sq[j0 + wave * 32 + 16 + kgrp * 4];
    float sqv[2][4] = { { sqa.x, sqa.y, sqa.z, sqa.w }, { sqb.x, sqb.y, sqb.z, sqb.w } };

    // self-pair only possible when the j-chunk equals this block's i-panel range
    const bool selfchunk = (j0 == rbase);

#define EPI_SLOT(fi, fj, r, ACC, CHECK)                                         \
    {                                                                           \
      const int jg = j0 + wave * 32 + (fj) * 16 + kgrp * 4 + (r);               \
      float d = fmaf(-2.0f, (ACC)[fi][r], sqv[fj][r]);                          \
      uint32_t u = __float_as_uint(d);                                          \
      u ^= (uint32_t)((int32_t)u >> 31) | 0x80000000u;                          \
      uint32_t key = (u & 0xFFFFC000u) | (uint32_t)jg;                          \
      if (!(CHECK) || jg != (rbase + (fi) * 16 + l15)) INS5K(keys[fi], key);    \
    }

    if (selfchunk) {
      #pragma unroll
      for (int fi = 0; fi < 16; ++fi) {
        #pragma unroll
        for (int r = 0; r < 4; ++r) EPI_SLOT(fi, 0, r, acc0, true)
        #pragma unroll
        for (int r = 0; r < 4; ++r) EPI_SLOT(fi, 1, r, acc1, true)
      }
    } else {
      #pragma unroll
      for (int fi = 0; fi < 16; ++fi) {
        #pragma unroll
        for (int r = 0; r < 4; ++r) EPI_SLOT(fi, 0, r, acc0, false)
        #pragma unroll
        for (int r = 0; r < 4; ++r) EPI_SLOT(fi, 1, r, acc1, false)
      }
    }
#undef EPI_SLOT
  }

  // ---- merge 4 kgrp partials within each wave (shuffle butterfly, lane bits 4,5)
  #pragma unroll
  for (int fi = 0; fi < 16; ++fi) {
    #pragma unroll
    for (int m = 16; m <= 32; m <<= 1) {
      uint32_t ok[5];
      #pragma unroll
      for (int s = 0; s < 5; ++s)
        ok[s] = (uint32_t)__shfl_xor((int)keys[fi][s], m);
      #pragma unroll
      for (int s = 0; s < 5; ++s) INS5K(keys[fi], ok[s]);
    }
  }

  // ---- 8 wave-partials x 5 keys per row -> LDS -> top-8 candidates for this quarter
  __syncthreads();   // i-panel reads done; reuse LDS as M
  if (kgrp == 0) {
    #pragma unroll
    for (int fi = 0; fi < 16; ++fi) {
      const int row = fi * 16 + l15;
      #pragma unroll
      for (int s = 0; s < 5; ++s)
        M[row * 40 + wave * 5 + s] = keys[fi][s];
    }
  }
  __syncthreads();
  if (tid < 256) {
    const int irow = rbase + tid;
    int* co = &cand[(size_t)irow * NC2 + quart * NCQ];
    #pragma unroll 1
    for (int s = 0; s < NCQ; ++s) {
      uint32_t best = 0xFFFFFFFFu; int bestt = 0;
      #pragma unroll 1
      for (int t = 0; t < 40; ++t) {
        uint32_t v = M[tid * 40 + t];
        if (v < best) { best = v; bestt = t; }
      }
      M[tid * 40 + bestt] = 0xFFFFFFFFu;
      co[s] = (int)(best & 0x3FFFu);
    }
  }
}

// ===================== exact fp32 rescore of 32 candidates -> top-5 =====================
// 128 threads (2 waves) per row: 4 lanes per candidate, 64 dims each. Ranking identical
// to the round-2 exact fp32 kernel (d = sq[j] - 2*dot, tie -> lower index).
__global__ __launch_bounds__(128) void rescore_kernel(
    const float* __restrict__ h, const float* __restrict__ sq,
    const int* __restrict__ cand, int* __restrict__ nbr)
{
  __shared__ float hi_s[HD];
  __shared__ float dv[NC2];
  __shared__ int   di[NC2];
  const int i = blockIdx.x;
  const int t = threadIdx.x;             // 0..127
  if (t < 64) *(float4*)&hi_s[t * 4] = *(const float4*)&h[(size_t)i * HD + t * 4];
  __syncthreads();
  const int c = t >> 2, q = t & 3;       // candidate c (0..31), quarter q
  const int j = cand[(size_t)i * NC2 + c];
  float s = 0.f;
  const float4* hj  = (const float4*)&h[(size_t)j * HD + q * 64];
  const float4* hi4 = (const float4*)&hi_s[q * 64];
  #pragma unroll
  for (int u = 0; u < 16; ++u) {
    float4 a = hi4[u], b = hj[u];
    s = fmaf(a.x, b.x, s); s = fmaf(a.y, b.y, s);
    s = fmaf(a.z, b.z, s); s = fmaf(a.w, b.w, s);
  }
  s += __shfl_down(s, 1);
  s += __shfl_down(s, 2);
  if (q == 0) { dv[c] = fmaf(-2.0f, s, sq[j]); di[c] = j; }
  __syncthreads();
  if (t == 0) {
    #pragma unroll 1
    for (int sidx = 0; sidx < KNN; ++sidx) {
      float bestv = 3.0e38f; int bestid = 0x7fffffff; int bestc = 0;
      #pragma unroll 1
      for (int u = 0; u < NC2; ++u) {
        float v = dv[u]; int id = di[u];
        if (v < bestv || (v == bestv && id < bestid)) { bestv = v; bestid = id; bestc = u; }
      }
      dv[bestc] = 3.0e38f;
      nbr[i * KNN + sidx] = bestid;
    }
  }
}

// ===================== graph build =====================
__global__ void count_kernel(const int* __restrict__ nbr, int* __restrict__ cnt)
{
  int e = blockIdx.x * 256 + threadIdx.x;
  if (e < NN * KNN) atomicAdd(&cnt[nbr[e]], 1);
}

__global__ void dinv_kernel(const int* __restrict__ cnt, float* __restrict__ dinv)
{
  int i = blockIdx.x * 256 + threadIdx.x;
  if (i < NN) dinv[i] = 1.0f / sqrtf((float)(cnt[i] + KNN + 1));  // deg = indeg + K + 1
}

__global__ __launch_bounds__(256) void scan_kernel(const int* __restrict__ cnt, int* __restrict__ off)
{
  __shared__ int ps[256];
  const int t = threadIdx.x;
  int s = 0;
  for (int i = 0; i < 64; ++i) s += cnt[t * 64 + i];
  ps[t] = s;
  __syncthreads();
  if (t == 0) {
    int run = 0;
    for (int q = 0; q < 256; ++q) { int v = ps[q]; ps[q] = run; run += v; }
  }
  __syncthreads();
  int base = ps[t];
  for (int i = 0; i < 64; ++i) { off[t * 64 + i] = base; base += cnt[t * 64 + i]; }
}

__global__ void fill_rev(const int* __restrict__ nbr, const int* __restrict__ off,
                         int* __restrict__ cur, int* __restrict__ rev)
{
  int e = blockIdx.x * 256 + threadIdx.x;
  if (e < NN * KNN) {
    int i = e / KNN;
    int c = nbr[e];
    int s = atomicAdd(&cur[c], 1);
    rev[off[c] + s] = i;
  }
}

// ===================== GCN aggregation (pure gather via reverse CSR) =====================
__global__ __launch_bounds__(64) void aggregate(
    const float* __restrict__ g, const int* __restrict__ nbr,
    const int* __restrict__ rev, const int* __restrict__ off, const int* __restrict__ cnt,
    const float* __restrict__ dinv, const float* __restrict__ bias,
    float* __restrict__ out, int do_relu)
{
  const int c = blockIdx.x;
  const int l = threadIdx.x;
  const float4* g4 = (const float4*)g;
  float4 v = g4[(size_t)c * (HD / 4) + l];
  float ax = v.x, ay = v.y, az = v.z, aw = v.w;
  #pragma unroll
  for (int k = 0; k < KNN; ++k) {
    int r = nbr[c * KNN + k];
    float4 u = g4[(size_t)r * (HD / 4) + l];
    ax += u.x; ay += u.y; az += u.z; aw += u.w;
  }
  const int o0 = off[c], o1 = o0 + cnt[c];
  for (int j = o0; j < o1; ++j) {
    int r = rev[j];
    float4 u = g4[(size_t)r * (HD / 4) + l];
    ax += u.x; ay += u.y; az += u.z; aw += u.w;
  }
  const float dc = dinv[c];
  float4 b = ((const float4*)bias)[l];
  float rx = ax * dc + b.x, ry = ay * dc + b.y, rz = az * dc + b.z, rw = aw * dc + b.w;
  if (do_relu) {
    rx = fmaxf(rx, 0.0f); ry = fmaxf(ry, 0.0f);
    rz = fmaxf(rz, 0.0f); rw = fmaxf(rw, 0.0f);
  }
  float4 o; o.x = rx; o.y = ry; o.z = rz; o.w = rw;
  ((float4*)out)[(size_t)c * (HD / 4) + l] = o;
}

// ===================== mean-pool + classifier =====================
__global__ __launch_bounds__(256) void colsum_kernel(const float* __restrict__ a, float* __restrict__ colsum)
{
  const int f = threadIdx.x;
  const int r0 = blockIdx.x * 64;
  float s = 0.0f;
  for (int r = 0; r < 64; ++r) s += a[(size_t)(r0 + r) * HD + f];
  atomicAdd(&colsum[f], s);
}

__global__ __launch_bounds__(256) void final_kernel(
    const float* __restrict__ colsum, const float* __restrict__ Wc,
    const float* __restrict__ bc, float* __restrict__ out)
{
  __shared__ float s0[256], s1[256];
  const int f = threadIdx.x;
  float bag = colsum[f] * (1.0f / (float)NN);
  s0[f] = bag * Wc[f * 2 + 0];
  s1[f] = bag * Wc[f * 2 + 1];
  __syncthreads();
  for (int st = 128; st; st >>= 1) {
    if (f < st) { s0[f] += s0[f + st]; s1[f] += s1[f + st]; }
    __syncthreads();
  }
  if (f == 0) { out[0] = s0[0] + bc[0]; out[1] = s1[0] + bc[1]; }
}

// ===================== launch =====================
extern "C" void kernel_launch(void* const* d_in, const int* in_sizes, int n_in,
                              void* d_out, int out_size, void* d_ws, size_t ws_size,
                              hipStream_t stream)
{
  const float* x   = (const float*)d_in[0];
  const float* Wp  = (const float*)d_in[1];
  const float* bp  = (const float*)d_in[2];
  const float* Wg1 = (const float*)d_in[3];
  const float* bg1 = (const float*)d_in[4];
  const float* Wg2 = (const float*)d_in[5];
  const float* bg2 = (const float*)d_in[6];
  const float* Wc  = (const float*)d_in[7];
  const float* bc  = (const float*)d_in[8];
  float* out = (float*)d_out;

  float* ws    = (float*)d_ws;
  float* h     = ws;                                // N*HD f32
  float* g     = ws + (size_t)NN * HD;              // N*HD f32 (written step 8)
  float* h1    = ws + 2 * (size_t)NN * HD;          // N*HD f32 (written step 9)
  float* agg2  = h;                                 // reuse
  float* sq    = ws + 3 * (size_t)NN * HD;          // N
  float* dinv  = sq + NN;                           // N
  float* colsum= dinv + NN;                         // HD
  int* nbr = (int*)(colsum + HD);                   // N*KNN
  int* cnt = nbr + NN * KNN;                        // N
  int* off = cnt + NN;                              // N
  int* cur = off + NN;                              // N
  int* rev = cur + NN;                              // N*KNN
  // bf16 hi lives in g region (dead until step 8, after kNN phase)
  ushort* hhi = (ushort*)g;                         // first 8.4 MB of g region
  // candidate list in upper quarter of g region (offset 12.6 MB)
  int* cand = (int*)(g + (size_t)NN * HD * 3 / 4);  // N*NC2 ints = 2 MB

  // 1. h = relu(x @ W_proj + b_proj)
  gemm_4x8<true, true, false><<<dim3(NN / 64, HD / 128), dim3(256), 0, stream>>>(
      x, Wp, bp, nullptr, h, NN, HD, IND);
  // 2. sq[i] = ||h_i||^2 fused with bf16 cast (single pass over h)
  sq_split_kernel<<<dim3(NN / 4), dim3(256), 0, stream>>>(h, sq, hhi);
  // 3a. approx top-8 candidates per row per j-quarter (256-row panels, halved traffic)
  dist_topk_mfma<<<dim3(NN / RPAN * NQ), dim3(512), 0, stream>>>(hhi, sq, cand);
  // 3b. exact fp32 rescore of 32 candidates -> top-5
  rescore_kernel<<<dim3(NN), dim3(128), 0, stream>>>(h, sq, cand, nbr);
  // 4. in-degree counts
  hipMemsetAsync(cnt, 0, NN * sizeof(int), stream);
  count_kernel<<<dim3((NN * KNN) / 256), dim3(256), 0, stream>>>(nbr, cnt);
  // 5. dinv
  dinv_kernel<<<dim3(NN / 256), dim3(256), 0, stream>>>(cnt, dinv);
  // 6. CSR offsets
  scan_kernel<<<dim3(1), dim3(256), 0, stream>>>(cnt, off);
  // 7. reverse adjacency
  hipMemsetAsync(cur, 0, NN * sizeof(int), stream);
  fill_rev<<<dim3((NN * KNN) / 256), dim3(256), 0, stream>>>(nbr, off, cur, rev);
  // 8. g = (h @ W_g1) * dinv[row]
  gemm_4x8<false, false, true><<<dim3(NN / 64, HD / 128), dim3(256), 0, stream>>>(
      h, Wg1, nullptr, dinv, g, NN, HD, HD);
  // 9. h1 = relu(agg(g) + b_g1)
  aggregate<<<dim3(NN), dim3(64), 0, stream>>>(g, nbr, rev, off, cnt, dinv, bg1, h1, 1);
  // 10. g = (h1 @ W_g2) * dinv[row]
  gemm_4x8<false, false, true><<<dim3(NN / 64, HD / 128), dim3(256), 0, stream>>>(
      h1, Wg2, nullptr, dinv, g, NN, HD, HD);
  // 11. agg2 = agg(g) + b_g2
  aggregate<<<dim3(NN), dim3(64), 0, stream>>>(g, nbr, rev, off, cnt, dinv, bg2, agg2, 0);
  // 12/13. mean-pool + classifier
  hipMemsetAsync(colsum, 0, HD * sizeof(float), stream);
  colsum_kernel<<<dim3(NN / 64), dim3(256), 0, stream>>>(agg2, colsum);
  final_kernel<<<dim3(1), dim3(256), 0, stream>>>(colsum, Wc, bc, out);
}

// Round 15
// 1592.659 us; speedup vs baseline: 1.3243x; 1.3243x over previous
//
#include <hip/hip_runtime.h>
#include <cstdint>
#include <cstddef>

#define NN 16384
#define IND 1024
#define HD 256
#define KNN 5
#define NQ 4        // j quarters
#define NCQ 8       // candidates kept per quarter
#define NC2 32      // total candidates per row
#define RPAN 256    // i-rows per panel

typedef __attribute__((ext_vector_type(4))) float f32x4;
typedef __attribute__((ext_vector_type(8))) short bf16x8;

// ===================== GEMM: C = op(A@B [+bias][*rowscale[m]]) =====================
// 64x128 tile, 4x8 micro, 256 threads. A:MxK row-major, B:KxN row-major.
template<bool RELU, bool BIAS, bool RS>
__global__ __launch_bounds__(256) void gemm_4x8(
    const float* __restrict__ A, const float* __restrict__ B,
    const float* __restrict__ bias, const float* __restrict__ rowscale,
    float* __restrict__ C, int M, int Nc, int K)
{
  __shared__ float As[16][68];
  __shared__ float Bs[16][132];
  const int tid = threadIdx.x;
  const int tx = tid & 15, ty = tid >> 4;
  const int m0 = blockIdx.x * 64, n0 = blockIdx.y * 128;

  float acc[4][8];
  #pragma unroll
  for (int i = 0; i < 4; ++i)
    #pragma unroll
    for (int j = 0; j < 8; ++j) acc[i][j] = 0.0f;

  const int am  = tid >> 2;
  const int akq = (tid & 3) * 4;

  for (int kb = 0; kb < K; kb += 16) {
    {
      float4 v = *(const float4*)&A[(size_t)(m0 + am) * K + kb + akq];
      As[akq + 0][am] = v.x; As[akq + 1][am] = v.y;
      As[akq + 2][am] = v.z; As[akq + 3][am] = v.w;
    }
    #pragma unroll
    for (int c = 0; c < 2; ++c) {
      int idx = tid + c * 256;
      int k = idx >> 5;
      int f = idx & 31;
      float4 v = *(const float4*)&B[(size_t)(kb + k) * Nc + n0 + f * 4];
      *(float4*)&Bs[k][f * 4] = v;
    }
    __syncthreads();
    #pragma unroll
    for (int k = 0; k < 16; ++k) {
      float a[4], b[8];
      *(float4*)&a[0] = *(const float4*)&As[k][ty * 4];
      *(float4*)&b[0] = *(const float4*)&Bs[k][tx * 4];
      *(float4*)&b[4] = *(const float4*)&Bs[k][64 + tx * 4];
      #pragma unroll
      for (int i = 0; i < 4; ++i)
        #pragma unroll
        for (int j = 0; j < 8; ++j)
          acc[i][j] = fmaf(a[i], b[j], acc[i][j]);
    }
    __syncthreads();
  }

  float bvals[8];
  if (BIAS) {
    *(float4*)&bvals[0] = *(const float4*)&bias[n0 + tx * 4];
    *(float4*)&bvals[4] = *(const float4*)&bias[n0 + 64 + tx * 4];
  }
  #pragma unroll
  for (int i = 0; i < 4; ++i) {
    int m = m0 + ty * 4 + i;
    float rs = RS ? rowscale[m] : 1.0f;
    float o[8];
    #pragma unroll
    for (int j = 0; j < 8; ++j) {
      float v = acc[i][j];
      if (BIAS) v += bvals[j];
      if (RS) v *= rs;
      if (RELU) v = fmaxf(v, 0.0f);
      o[j] = v;
    }
    *(float4*)&C[(size_t)m * Nc + n0 + tx * 4]      = *(float4*)&o[0];
    *(float4*)&C[(size_t)m * Nc + n0 + 64 + tx * 4] = *(float4*)&o[4];
  }
}

// ===================== fp32 -> bf16 helpers =====================
__device__ __forceinline__ ushort f2bf(float f) {
  uint32_t u = __float_as_uint(f);
  uint32_t r = (u + 0x7fffu + ((u >> 16) & 1u)) >> 16;
  return (ushort)r;
}

// ===================== fused row-norms + bf16 cast (one pass over h) ==========
__global__ __launch_bounds__(256) void sq_split_kernel(
    const float* __restrict__ h, float* __restrict__ sq, ushort* __restrict__ hhi)
{
  const int w = threadIdx.x >> 6, l = threadIdx.x & 63;
  const int r = blockIdx.x * 4 + w;
  float4 v = *(const float4*)&h[(size_t)r * HD + l * 4];
  float s = v.x * v.x + v.y * v.y + v.z * v.z + v.w * v.w;
  #pragma unroll
  for (int o = 32; o; o >>= 1) s += __shfl_down(s, o);
  if (l == 0) sq[r] = s;
  ushort4 H; H.x = f2bf(v.x); H.y = f2bf(v.y); H.z = f2bf(v.z); H.w = f2bf(v.w);
  *(ushort4*)&hhi[(size_t)r * HD + l * 4] = H;
}

// sorted u32-key top-5 insert (k0<k1<...<k4); key embeds index -> unique, and
// for equal distance-bits lower index = lower key.
#define INS5K(v, k) do {                                                \
    if ((k) < v[4]) {                                                   \
      if ((k) < v[0])      { v[4]=v[3];v[3]=v[2];v[2]=v[1];v[1]=v[0];v[0]=(k); } \
      else if ((k) < v[1]) { v[4]=v[3];v[3]=v[2];v[2]=v[1];v[1]=(k); }  \
      else if ((k) < v[2]) { v[4]=v[3];v[3]=v[2];v[2]=(k); }            \
      else if ((k) < v[3]) { v[4]=v[3];v[3]=(k); }                      \
      else                 { v[4]=(k); }                                \
    }                                                                   \
  } while (0)

// ===================== MFMA pairwise-distance -> top-8 candidates per j-quarter ========
// FILTER pass (validated r9-r13, absmax 0.0): 1-term bf16 Gram, key = monotone-u32(d)
// high 18 bits | j (NN=2^14). Exact fp32 rescore recovers the true top-5.
// r12 lesson: dist time ~ (FETCH+WRITE)/2.6TB/s L3-service ceiling -> reduce LOGICAL
// traffic with R=256 panels (j-traffic 537MB). r13 lesson: fi=16 acc(128)+keys(80)
// exceeded the 256 VGPR/wave budget -> 1.2GB scratch WRITE. Fix: TWO SEQUENTIAL
// fi-PASSES per j-chunk (rows 0-127 then 128-255); the second pass re-reads the same
// 128KB j-chunk (L1/L2-hot, no extra L2-miss bytes). Live regs: keys 80 + acc 64 +
// temps ~= 180 < 256 -> no spill.
// Block: 256 i-rows (bf16 LDS panel 132KB -> 1 block/CU), 512 threads, grid 256.
// quart = bid&3, panel = bid>>2. A-operand direct from global, no barriers in K-loop,
// no manual conditional prefetch (r8 lesson).
// Lane owns i = (HBASE+fi)*16+(lane&15); j = wave*32 + fj*16 + (lane>>4)*4 + reg.
__global__ __launch_bounds__(512, 2) void dist_topk_mfma(
    const ushort* __restrict__ hhi, const float* __restrict__ sq, int* __restrict__ cand)
{
  // iHi [256][264 us] = 135168 B; merge M (uint, aliases @0): 256 x 40 = 40960 B.
  __shared__ char smem[135168];
  ushort*   iHi = (ushort*)smem;
  uint32_t* M   = (uint32_t*)smem;

  const int tid  = threadIdx.x;
  const int wave = tid >> 6, lane = tid & 63;
  const int l15  = lane & 15, kgrp = lane >> 4;
  const int panel = blockIdx.x >> 2;
  const int quart = blockIdx.x & 3;
  const int rbase = panel * RPAN;
  const int jbeg  = quart * (NN / NQ);

  // ---- stage i-panel (256 x 256 bf16), once: 2 threads/row, 128 us (16 x uint4) each
  {
    const int r = tid >> 1, q = tid & 1;
    const uint4* sH = (const uint4*)&hhi[(size_t)(rbase + r) * HD + q * 128];
    uint4* dH = (uint4*)&iHi[r * 264 + q * 128];
    #pragma unroll
    for (int c = 0; c < 16; ++c) dH[c] = sH[c];
  }
  __syncthreads();

  uint32_t keys0[8][5], keys1[8][5];
  #pragma unroll
  for (int i = 0; i < 8; ++i)
    #pragma unroll
    for (int s = 0; s < 5; ++s) { keys0[i][s] = 0xFFFFFFFFu; keys1[i][s] = 0xFFFFFFFFu; }

  for (int j0 = jbeg; j0 < jbeg + NN / NQ; j0 += 256) {
    float4 sqa = *(const float4*)&sq[j0 + wave * 32 + kgrp * 4];
    float4 sqb = *(const float4*)&sq[j0 + wave * 32 + 16 + kgrp * 4];
    float sqv[2][4] = { { sqa.x, sqa.y, sqa.z, sqa.w }, { sqb.x, sqb.y, sqb.z, sqb.w } };
    const bool selfchunk = (j0 == rbase);

    // One fi-half: 8 i-row-groups, acc[8][2] (64 VGPR), folds into KEYS.
#define HALF_PASS(KEYS, HBASE)                                                        \
    {                                                                                 \
      f32x4 acc0[8], acc1[8];                                                         \
      _Pragma("unroll")                                                               \
      for (int fi = 0; fi < 8; ++fi) {                                                \
        acc0[fi] = (f32x4){0.f, 0.f, 0.f, 0.f};                                       \
        acc1[fi] = (f32x4){0.f, 0.f, 0.f, 0.f};                                       \
      }                                                                               \
      _Pragma("unroll")                                                               \
      for (int kb = 0; kb < 8; ++kb) {                                                \
        bf16x8 a0 = *(const bf16x8*)&hhi[(size_t)(j0 + wave * 32 + l15) * HD + kb * 32 + kgrp * 8];        \
        bf16x8 a1 = *(const bf16x8*)&hhi[(size_t)(j0 + wave * 32 + 16 + l15) * HD + kb * 32 + kgrp * 8];   \
        _Pragma("unroll")                                                             \
        for (int fi = 0; fi < 8; ++fi) {                                              \
          bf16x8 b = *(const bf16x8*)&iHi[(((HBASE) + fi) * 16 + l15) * 264 + kb * 32 + kgrp * 8];         \
          acc0[fi] = __builtin_amdgcn_mfma_f32_16x16x32_bf16(a0, b, acc0[fi], 0, 0, 0);                    \
          acc1[fi] = __builtin_amdgcn_mfma_f32_16x16x32_bf16(a1, b, acc1[fi], 0, 0, 0);                    \
        }                                                                             \
      }                                                                               \
      _Pragma("unroll")                                                               \
      for (int fi = 0; fi < 8; ++fi) {                                                \
        const int ig = rbase + ((HBASE) + fi) * 16 + l15;                             \
        _Pragma("unroll")                                                             \
        for (int r = 0; r < 4; ++r) {                                                 \
          const int jg = j0 + wave * 32 + kgrp * 4 + r;                               \
          float d = fmaf(-2.0f, acc0[fi][r], sqv[0][r]);                              \
          uint32_t u = __float_as_uint(d);                                            \
          u ^= (uint32_t)((int32_t)u >> 31) | 0x80000000u;                            \
          uint32_t key = (u & 0xFFFFC000u) | (uint32_t)jg;                            \
          if (!selfchunk || jg != ig) INS5K(KEYS[fi], key);                           \
        }                                                                             \
        _Pragma("unroll")                                                             \
        for (int r = 0; r < 4; ++r) {                                                 \
          const int jg = j0 + wave * 32 + 16 + kgrp * 4 + r;                          \
          float d = fmaf(-2.0f, acc1[fi][r], sqv[1][r]);                              \
          uint32_t u = __float_as_uint(d);                                            \
          u ^= (uint32_t)((int32_t)u >> 31) | 0x80000000u;                            \
          uint32_t key = (u & 0xFFFFC000u) | (uint32_t)jg;                            \
          if (!selfchunk || jg != ig) INS5K(KEYS[fi], key);                           \
        }                                                                             \
      }                                                                               \
    }

    HALF_PASS(keys0, 0)
    HALF_PASS(keys1, 8)
#undef HALF_PASS
  }

  // ---- merge 4 kgrp partials within each wave (shuffle butterfly, lane bits 4,5)
  #pragma unroll
  for (int fi = 0; fi < 8; ++fi) {
    #pragma unroll
    for (int m = 16; m <= 32; m <<= 1) {
      uint32_t ok[5];
      #pragma unroll
      for (int s = 0; s < 5; ++s) ok[s] = (uint32_t)__shfl_xor((int)keys0[fi][s], m);
      #pragma unroll
      for (int s = 0; s < 5; ++s) INS5K(keys0[fi], ok[s]);
      #pragma unroll
      for (int s = 0; s < 5; ++s) ok[s] = (uint32_t)__shfl_xor((int)keys1[fi][s], m);
      #pragma unroll
      for (int s = 0; s < 5; ++s) INS5K(keys1[fi], ok[s]);
    }
  }

  // ---- 8 wave-partials x 5 keys per row -> LDS -> top-8 candidates for this quarter
  __syncthreads();   // i-panel reads done; reuse LDS as M
  if (kgrp == 0) {
    #pragma unroll
    for (int fi = 0; fi < 8; ++fi) {
      const int row0 = fi * 16 + l15;
      const int row1 = (8 + fi) * 16 + l15;
      #pragma unroll
      for (int s = 0; s < 5; ++s) {
        M[row0 * 40 + wave * 5 + s] = keys0[fi][s];
        M[row1 * 40 + wave * 5 + s] = keys1[fi][s];
      }
    }
  }
  __syncthreads();
  {
    const int irow = rbase + tid % 256;
    if (tid < 256) {
      int* co = &cand[(size_t)irow * NC2 + quart * NCQ];
      #pragma unroll 1
      for (int s = 0; s < NCQ; ++s) {
        uint32_t best = 0xFFFFFFFFu; int bestt = 0;
        #pragma unroll 1
        for (int t = 0; t < 40; ++t) {
          uint32_t v = M[(tid % 256) * 40 + t];
          if (v < best) { best = v; bestt = t; }
        }
        M[(tid % 256) * 40 + bestt] = 0xFFFFFFFFu;
        co[s] = (int)(best & 0x3FFFu);
      }
    }
  }
}

// ===================== exact fp32 rescore of 32 candidates -> top-5 =====================
// 128 threads (2 waves) per row: 4 lanes per candidate, 64 dims each. Ranking identical
// to the round-2 exact fp32 kernel (d = sq[j] - 2*dot, tie -> lower index).
__global__ __launch_bounds__(128) void rescore_kernel(
    const float* __restrict__ h, const float* __restrict__ sq,
    const int* __restrict__ cand, int* __restrict__ nbr)
{
  __shared__ float hi_s[HD];
  __shared__ float dv[NC2];
  __shared__ int   di[NC2];
  const int i = blockIdx.x;
  const int t = threadIdx.x;             // 0..127
  if (t < 64) *(float4*)&hi_s[t * 4] = *(const float4*)&h[(size_t)i * HD + t * 4];
  __syncthreads();
  const int c = t >> 2, q = t & 3;       // candidate c (0..31), quarter q
  const int j = cand[(size_t)i * NC2 + c];
  float s = 0.f;
  const float4* hj  = (const float4*)&h[(size_t)j * HD + q * 64];
  const float4* hi4 = (const float4*)&hi_s[q * 64];
  #pragma unroll
  for (int u = 0; u < 16; ++u) {
    float4 a = hi4[u], b = hj[u];
    s = fmaf(a.x, b.x, s); s = fmaf(a.y, b.y, s);
    s = fmaf(a.z, b.z, s); s = fmaf(a.w, b.w, s);
  }
  s += __shfl_down(s, 1);
  s += __shfl_down(s, 2);
  if (q == 0) { dv[c] = fmaf(-2.0f, s, sq[j]); di[c] = j; }
  __syncthreads();
  if (t == 0) {
    #pragma unroll 1
    for (int sidx = 0; sidx < KNN; ++sidx) {
      float bestv = 3.0e38f; int bestid = 0x7fffffff; int bestc = 0;
      #pragma unroll 1
      for (int u = 0; u < NC2; ++u) {
        float v = dv[u]; int id = di[u];
        if (v < bestv || (v == bestv && id < bestid)) { bestv = v; bestid = id; bestc = u; }
      }
      dv[bestc] = 3.0e38f;
      nbr[i * KNN + sidx] = bestid;
    }
  }
}

// ===================== graph build =====================
__global__ void count_kernel(const int* __restrict__ nbr, int* __restrict__ cnt)
{
  int e = blockIdx.x * 256 + threadIdx.x;
  if (e < NN * KNN) atomicAdd(&cnt[nbr[e]], 1);
}

__global__ void dinv_kernel(const int* __restrict__ cnt, float* __restrict__ dinv)
{
  int i = blockIdx.x * 256 + threadIdx.x;
  if (i < NN) dinv[i] = 1.0f / sqrtf((float)(cnt[i] + KNN + 1));  // deg = indeg + K + 1
}

__global__ __launch_bounds__(256) void scan_kernel(const int* __restrict__ cnt, int* __restrict__ off)
{
  __shared__ int ps[256];
  const int t = threadIdx.x;
  int s = 0;
  for (int i = 0; i < 64; ++i) s += cnt[t * 64 + i];
  ps[t] = s;
  __syncthreads();
  if (t == 0) {
    int run = 0;
    for (int q = 0; q < 256; ++q) { int v = ps[q]; ps[q] = run; run += v; }
  }
  __syncthreads();
  int base = ps[t];
  for (int i = 0; i < 64; ++i) { off[t * 64 + i] = base; base += cnt[t * 64 + i]; }
}

__global__ void fill_rev(const int* __restrict__ nbr, const int* __restrict__ off,
                         int* __restrict__ cur, int* __restrict__ rev)
{
  int e = blockIdx.x * 256 + threadIdx.x;
  if (e < NN * KNN) {
    int i = e / KNN;
    int c = nbr[e];
    int s = atomicAdd(&cur[c], 1);
    rev[off[c] + s] = i;
  }
}

// ===================== GCN aggregation (pure gather via reverse CSR) =====================
__global__ __launch_bounds__(64) void aggregate(
    const float* __restrict__ g, const int* __restrict__ nbr,
    const int* __restrict__ rev, const int* __restrict__ off, const int* __restrict__ cnt,
    const float* __restrict__ dinv, const float* __restrict__ bias,
    float* __restrict__ out, int do_relu)
{
  const int c = blockIdx.x;
  const int l = threadIdx.x;
  const float4* g4 = (const float4*)g;
  float4 v = g4[(size_t)c * (HD / 4) + l];
  float ax = v.x, ay = v.y, az = v.z, aw = v.w;
  #pragma unroll
  for (int k = 0; k < KNN; ++k) {
    int r = nbr[c * KNN + k];
    float4 u = g4[(size_t)r * (HD / 4) + l];
    ax += u.x; ay += u.y; az += u.z; aw += u.w;
  }
  const int o0 = off[c], o1 = o0 + cnt[c];
  for (int j = o0; j < o1; ++j) {
    int r = rev[j];
    float4 u = g4[(size_t)r * (HD / 4) + l];
    ax += u.x; ay += u.y; az += u.z; aw += u.w;
  }
  const float dc = dinv[c];
  float4 b = ((const float4*)bias)[l];
  float rx = ax * dc + b.x, ry = ay * dc + b.y, rz = az * dc + b.z, rw = aw * dc + b.w;
  if (do_relu) {
    rx = fmaxf(rx, 0.0f); ry = fmaxf(ry, 0.0f);
    rz = fmaxf(rz, 0.0f); rw = fmaxf(rw, 0.0f);
  }
  float4 o; o.x = rx; o.y = ry; o.z = rz; o.w = rw;
  ((float4*)out)[(size_t)c * (HD / 4) + l] = o;
}

// ===================== mean-pool + classifier =====================
__global__ __launch_bounds__(256) void colsum_kernel(const float* __restrict__ a, float* __restrict__ colsum)
{
  const int f = threadIdx.x;
  const int r0 = blockIdx.x * 64;
  float s = 0.0f;
  for (int r = 0; r < 64; ++r) s += a[(size_t)(r0 + r) * HD + f];
  atomicAdd(&colsum[f], s);
}

__global__ __launch_bounds__(256) void final_kernel(
    const float* __restrict__ colsum, const float* __restrict__ Wc,
    const float* __restrict__ bc, float* __restrict__ out)
{
  __shared__ float s0[256], s1[256];
  const int f = threadIdx.x;
  float bag = colsum[f] * (1.0f / (float)NN);
  s0[f] = bag * Wc[f * 2 + 0];
  s1[f] = bag * Wc[f * 2 + 1];
  __syncthreads();
  for (int st = 128; st; st >>= 1) {
    if (f < st) { s0[f] += s0[f + st]; s1[f] += s1[f + st]; }
    __syncthreads();
  }
  if (f == 0) { out[0] = s0[0] + bc[0]; out[1] = s1[0] + bc[1]; }
}

// ===================== launch =====================
extern "C" void kernel_launch(void* const* d_in, const int* in_sizes, int n_in,
                              void* d_out, int out_size, void* d_ws, size_t ws_size,
                              hipStream_t stream)
{
  const float* x   = (const float*)d_in[0];
  const float* Wp  = (const float*)d_in[1];
  const float* bp  = (const float*)d_in[2];
  const float* Wg1 = (const float*)d_in[3];
  const float* bg1 = (const float*)d_in[4];
  const float* Wg2 = (const float*)d_in[5];
  const float* bg2 = (const float*)d_in[6];
  const float* Wc  = (const float*)d_in[7];
  const float* bc  = (const float*)d_in[8];
  float* out = (float*)d_out;

  float* ws    = (float*)d_ws;
  float* h     = ws;                                // N*HD f32
  float* g     = ws + (size_t)NN * HD;              // N*HD f32 (written step 8)
  float* h1    = ws + 2 * (size_t)NN * HD;          // N*HD f32 (written step 9)
  float* agg2  = h;                                 // reuse
  float* sq    = ws + 3 * (size_t)NN * HD;          // N
  float* dinv  = sq + NN;                           // N
  float* colsum= dinv + NN;                         // HD
  int* nbr = (int*)(colsum + HD);                   // N*KNN
  int* cnt = nbr + NN * KNN;                        // N
  int* off = cnt + NN;                              // N
  int* cur = off + NN;                              // N
  int* rev = cur + NN;                              // N*KNN
  // bf16 hi lives in g region (dead until step 8, after kNN phase)
  ushort* hhi = (ushort*)g;                         // first 8.4 MB of g region
  // candidate list in upper quarter of g region (offset 12.6 MB)
  int* cand = (int*)(g + (size_t)NN * HD * 3 / 4);  // N*NC2 ints = 2 MB

  // 1. h = relu(x @ W_proj + b_proj)
  gemm_4x8<true, true, false><<<dim3(NN / 64, HD / 128), dim3(256), 0, stream>>>(
      x, Wp, bp, nullptr, h, NN, HD, IND);
  // 2. sq[i] = ||h_i||^2 fused with bf16 cast (single pass over h)
  sq_split_kernel<<<dim3(NN / 4), dim3(256), 0, stream>>>(h, sq, hhi);
  // 3a. approx top-8 candidates per row per j-quarter (256-row panels, 2-pass fi)
  dist_topk_mfma<<<dim3(NN / RPAN * NQ), dim3(512), 0, stream>>>(hhi, sq, cand);
  // 3b. exact fp32 rescore of 32 candidates -> top-5
  rescore_kernel<<<dim3(NN), dim3(128), 0, stream>>>(h, sq, cand, nbr);
  // 4. in-degree counts
  hipMemsetAsync(cnt, 0, NN * sizeof(int), stream);
  count_kernel<<<dim3((NN * KNN) / 256), dim3(256), 0, stream>>>(nbr, cnt);
  // 5. dinv
  dinv_kernel<<<dim3(NN / 256), dim3(256), 0, stream>>>(cnt, dinv);
  // 6. CSR offsets
  scan_kernel<<<dim3(1), dim3(256), 0, stream>>>(cnt, off);
  // 7. reverse adjacency
  hipMemsetAsync(cur, 0, NN * sizeof(int), stream);
  fill_rev<<<dim3((NN * KNN) / 256), dim3(256), 0, stream>>>(nbr, off, cur, rev);
  // 8. g = (h @ W_g1) * dinv[row]
  gemm_4x8<false, false, true><<<dim3(NN / 64, HD / 128), dim3(256), 0, stream>>>(
      h, Wg1, nullptr, dinv, g, NN, HD, HD);
  // 9. h1 = relu(agg(g) + b_g1)
  aggregate<<<dim3(NN), dim3(64), 0, stream>>>(g, nbr, rev, off, cnt, dinv, bg1, h1, 1);
  // 10. g = (h1 @ W_g2) * dinv[row]
  gemm_4x8<false, false, true><<<dim3(NN / 64, HD / 128), dim3(256), 0, stream>>>(
      h1, Wg2, nullptr, dinv, g, NN, HD, HD);
  // 11. agg2 = agg(g) + b_g2
  aggregate<<<dim3(NN), dim3(64), 0, stream>>>(g, nbr, rev, off, cnt, dinv, bg2, agg2, 0);
  // 12/13. mean-pool + classifier
  hipMemsetAsync(colsum, 0, HD * sizeof(float), stream);
  colsum_kernel<<<dim3(NN / 64), dim3(256), 0, stream>>>(agg2, colsum);
  final_kernel<<<dim3(1), dim3(256), 0, stream>>>(colsum, Wc, bc, out);
}

// Round 17
// 1089.730 us; speedup vs baseline: 1.9354x; 1.4615x over previous
//
#include <hip/hip_runtime.h>
#include <cstdint>
#include <cstddef>

#define NN 16384
#define IND 1024
#define HD 256
#define KNN 5
#define NCAND 16   // per j-half
#define NC2 32     // total candidates per row (2 halves)

typedef __attribute__((ext_vector_type(4))) float f32x4;
typedef __attribute__((ext_vector_type(8))) short bf16x8;

// ===================== fp32 -> bf16 helpers =====================
__device__ __forceinline__ ushort f2bf(float f) {
  uint32_t u = __float_as_uint(f);
  uint32_t r = (u + 0x7fffu + ((u >> 16) & 1u)) >> 16;
  return (ushort)r;
}
__device__ __forceinline__ float bf2f(ushort s) {
  return __uint_as_float(((uint32_t)s) << 16);
}

// ===================== MFMA GEMM via split-bf16 3-term =====================
// C[M][N] = op(A@B [+bias] [*rowscale[m]]); A: MxK f32 row-major, B: KxN f32 row-major.
// 3-term: A~Ah+Al, B~Bh+Bl; A@B ~ Ah@Bh + Ah@Bl + Al@Bh (rel err ~1e-7, same order as
// fp32 reduction reordering -- r2 evidence: absmax 0.0 under such perturbation).
// Tile 128x128, BK=32, 256 threads (4 waves). In-kernel hi/lo conversion at staging.
// Fragment mapping = the rescore-validated dist pattern: MFMA-A = m-row frag (k-contig),
// MFMA-B = n-row frag from TRANSPOSED B-tile; D[col = n-group l15][row = kgrp*4+reg].
template<bool RELU, bool BIAS, bool RS>
__global__ __launch_bounds__(256) void gemm_mfma(
    const float* __restrict__ A, const float* __restrict__ B,
    const float* __restrict__ bias, const float* __restrict__ rowscale,
    float* __restrict__ C, int M, int N, int K)
{
  __shared__ ushort Ahi[128 * 40], Alo[128 * 40];   // [m][k], row 40 us (80B, padded)
  __shared__ ushort Bhi[128 * 40], Blo[128 * 40];   // [n][k] transposed
  const int tid  = threadIdx.x;
  const int wave = tid >> 6, lane = tid & 63;
  const int l15  = lane & 15, kgrp = lane >> 4;
  const int m0 = blockIdx.x * 128, n0 = blockIdx.y * 128;

  f32x4 acc[8][2];
  #pragma unroll
  for (int fi = 0; fi < 8; ++fi)
    #pragma unroll
    for (int fj = 0; fj < 2; ++fj) acc[fi][fj] = (f32x4){0.f, 0.f, 0.f, 0.f};

  const int arow = tid >> 1, ahalf = tid & 1;       // A: 2 thr/row, 16 k each
  const int bn = tid >> 1, bkh = tid & 1;           // B: 2 thr/n-col, 16 k each

  for (int kb = 0; kb < K; kb += 32) {
    // stage A tile 128x32 -> hi/lo
    #pragma unroll
    for (int c = 0; c < 4; ++c) {
      float4 v = *(const float4*)&A[(size_t)(m0 + arow) * K + kb + ahalf * 16 + c * 4];
      int o = arow * 40 + ahalf * 16 + c * 4;
      ushort h0 = f2bf(v.x), h1 = f2bf(v.y), h2 = f2bf(v.z), h3 = f2bf(v.w);
      ushort4 H; H.x = h0; H.y = h1; H.z = h2; H.w = h3;
      ushort4 L; L.x = f2bf(v.x - bf2f(h0)); L.y = f2bf(v.y - bf2f(h1));
      L.z = f2bf(v.z - bf2f(h2)); L.w = f2bf(v.w - bf2f(h3));
      *(ushort4*)&Ahi[o] = H;
      *(ushort4*)&Alo[o] = L;
    }
    // stage B tile 32x128 transposed -> [n][k] hi/lo (global reads coalesced across lanes)
    #pragma unroll
    for (int i = 0; i < 16; ++i) {
      int k = bkh * 16 + i;
      float v = B[(size_t)(kb + k) * N + n0 + bn];
      ushort h = f2bf(v);
      Bhi[bn * 40 + k] = h;
      Blo[bn * 40 + k] = f2bf(v - bf2f(h));
    }
    __syncthreads();

    bf16x8 aH[2], aL[2];
    #pragma unroll
    for (int fj = 0; fj < 2; ++fj) {
      const int mr = wave * 32 + fj * 16 + l15;
      aH[fj] = *(const bf16x8*)&Ahi[mr * 40 + kgrp * 8];
      aL[fj] = *(const bf16x8*)&Alo[mr * 40 + kgrp * 8];
    }
    #pragma unroll
    for (int fi = 0; fi < 8; ++fi) {
      const int nr = fi * 16 + l15;
      bf16x8 bH = *(const bf16x8*)&Bhi[nr * 40 + kgrp * 8];
      bf16x8 bL = *(const bf16x8*)&Blo[nr * 40 + kgrp * 8];
      #pragma unroll
      for (int fj = 0; fj < 2; ++fj) {
        acc[fi][fj] = __builtin_amdgcn_mfma_f32_16x16x32_bf16(aH[fj], bH, acc[fi][fj], 0, 0, 0);
        acc[fi][fj] = __builtin_amdgcn_mfma_f32_16x16x32_bf16(aH[fj], bL, acc[fi][fj], 0, 0, 0);
        acc[fi][fj] = __builtin_amdgcn_mfma_f32_16x16x32_bf16(aL[fj], bH, acc[fi][fj], 0, 0, 0);
      }
    }
    __syncthreads();
  }

  // epilogue
  float bv[8];
  if (BIAS) {
    #pragma unroll
    for (int fi = 0; fi < 8; ++fi) bv[fi] = bias[n0 + fi * 16 + l15];
  }
  float rsv[2][4];
  if (RS) {
    #pragma unroll
    for (int fj = 0; fj < 2; ++fj)
      #pragma unroll
      for (int r = 0; r < 4; ++r)
        rsv[fj][r] = rowscale[m0 + wave * 32 + fj * 16 + kgrp * 4 + r];
  }
  #pragma unroll
  for (int fi = 0; fi < 8; ++fi) {
    const int n = n0 + fi * 16 + l15;
    #pragma unroll
    for (int fj = 0; fj < 2; ++fj) {
      #pragma unroll
      for (int r = 0; r < 4; ++r) {
        const int m = m0 + wave * 32 + fj * 16 + kgrp * 4 + r;
        float v = acc[fi][fj][r];
        if (BIAS) v += bv[fi];
        if (RS) v *= rsv[fj][r];
        if (RELU) v = fmaxf(v, 0.0f);
        C[(size_t)m * N + n] = v;
      }
    }
  }
}

// ===================== fused row-norms + bf16 hi/lo split (one pass over h) ==========
__global__ __launch_bounds__(256) void sq_split_kernel(
    const float* __restrict__ h, float* __restrict__ sq,
    ushort* __restrict__ hhi, ushort* __restrict__ hlo)
{
  const int w = threadIdx.x >> 6, l = threadIdx.x & 63;
  const int r = blockIdx.x * 4 + w;
  float4 v = *(const float4*)&h[(size_t)r * HD + l * 4];
  float s = v.x * v.x + v.y * v.y + v.z * v.z + v.w * v.w;
  #pragma unroll
  for (int o = 32; o; o >>= 1) s += __shfl_down(s, o);
  if (l == 0) sq[r] = s;
  ushort a0 = f2bf(v.x), a1 = f2bf(v.y), a2 = f2bf(v.z), a3 = f2bf(v.w);
  ushort b0 = f2bf(v.x - bf2f(a0)), b1 = f2bf(v.y - bf2f(a1));
  ushort b2 = f2bf(v.z - bf2f(a2)), b3 = f2bf(v.w - bf2f(a3));
  ushort4 H; H.x = a0; H.y = a1; H.z = a2; H.w = a3;
  ushort4 L; L.x = b0; L.y = b1; L.z = b2; L.w = b3;
  *(ushort4*)&hhi[(size_t)r * HD + l * 4] = H;
  *(ushort4*)&hlo[(size_t)r * HD + l * 4] = L;
}

// top-5 insertion ladder (strict < so earlier-inserted wins ties)
#define INS5(v, id, d, j) do {                                              \
    if ((d) < v[0]) {                                                       \
      v[4]=v[3]; id[4]=id[3]; v[3]=v[2]; id[3]=id[2];                       \
      v[2]=v[1]; id[2]=id[1]; v[1]=v[0]; id[1]=id[0];                       \
      v[0]=(d); id[0]=(j);                                                  \
    } else if ((d) < v[1]) {                                                \
      v[4]=v[3]; id[4]=id[3]; v[3]=v[2]; id[3]=id[2];                       \
      v[2]=v[1]; id[2]=id[1]; v[1]=(d); id[1]=(j);                          \
    } else if ((d) < v[2]) {                                                \
      v[4]=v[3]; id[4]=id[3]; v[3]=v[2]; id[3]=id[2]; v[2]=(d); id[2]=(j);  \
    } else if ((d) < v[3]) {                                                \
      v[4]=v[3]; id[4]=id[3]; v[3]=(d); id[3]=(j);                          \
    } else {                                                                \
      v[4]=(d); id[4]=(j);                                                  \
    }                                                                       \
  } while (0)

// ===================== MFMA pairwise-distance -> top-16 candidates per j-half ==========
// EXACT copy of the round-6 measured kernel (594us, FETCH 73MB, total 1168us).
// Gram via split-bf16 3-term; 128 i-rows LDS-resident; j-half streamed, A-operand
// direct from global; no barriers in K-loop. grid = (128 panels, 2 j-halves).
__global__ __launch_bounds__(512, 2) void dist_topk_mfma(
    const ushort* __restrict__ hhi, const ushort* __restrict__ hlo,
    const float* __restrict__ sq, int* __restrict__ cand)
{
  __shared__ char smem[135168];
  ushort* iHi = (ushort*)smem;
  ushort* iLo = (ushort*)(smem + 67584);
  float*  M   = (float*)smem;

  const int tid  = threadIdx.x;
  const int wave = tid >> 6, lane = tid & 63;
  const int l15  = lane & 15, kgrp = lane >> 4;
  const int rbase = blockIdx.x * 128;
  const int jbeg  = blockIdx.y * (NN / 2);

  {
    const int r = tid >> 2, q = tid & 3;
    const uint4* sH = (const uint4*)&hhi[(size_t)(rbase + r) * HD + q * 64];
    const uint4* sL = (const uint4*)&hlo[(size_t)(rbase + r) * HD + q * 64];
    uint4* dH = (uint4*)&iHi[r * 264 + q * 64];
    uint4* dL = (uint4*)&iLo[r * 264 + q * 64];
    #pragma unroll
    for (int c = 0; c < 8; ++c) { dH[c] = sH[c]; dL[c] = sL[c]; }
  }
  __syncthreads();

  float bv[8][5]; int bi[8][5];
  #pragma unroll
  for (int i = 0; i < 8; ++i)
    #pragma unroll
    for (int s = 0; s < 5; ++s) { bv[i][s] = 3.0e38f; bi[i][s] = 0; }

  for (int j0 = jbeg; j0 < jbeg + NN / 2; j0 += 256) {
    f32x4 acc[8][2];
    #pragma unroll
    for (int fi = 0; fi < 8; ++fi)
      #pragma unroll
      for (int fj = 0; fj < 2; ++fj) acc[fi][fj] = (f32x4){0.f, 0.f, 0.f, 0.f};

    #pragma unroll 2
    for (int kb = 0; kb < 8; ++kb) {
      bf16x8 aH[2], aL[2];
      #pragma unroll
      for (int fj = 0; fj < 2; ++fj) {
        const size_t jr = (size_t)(j0 + wave * 32 + fj * 16 + l15);
        aH[fj] = *(const bf16x8*)&hhi[jr * HD + kb * 32 + kgrp * 8];
        aL[fj] = *(const bf16x8*)&hlo[jr * HD + kb * 32 + kgrp * 8];
      }
      #pragma unroll
      for (int fi = 0; fi < 8; ++fi) {
        const int ir = fi * 16 + l15;
        bf16x8 bH = *(const bf16x8*)&iHi[ir * 264 + kb * 32 + kgrp * 8];
        bf16x8 bL = *(const bf16x8*)&iLo[ir * 264 + kb * 32 + kgrp * 8];
        #pragma unroll
        for (int fj = 0; fj < 2; ++fj) {
          acc[fi][fj] = __builtin_amdgcn_mfma_f32_16x16x32_bf16(aH[fj], bH, acc[fi][fj], 0, 0, 0);
          acc[fi][fj] = __builtin_amdgcn_mfma_f32_16x16x32_bf16(aH[fj], bL, acc[fi][fj], 0, 0, 0);
          acc[fi][fj] = __builtin_amdgcn_mfma_f32_16x16x32_bf16(aL[fj], bH, acc[fi][fj], 0, 0, 0);
        }
      }
    }

    float4 sqa = *(const float4*)&sq[j0 + wave * 32 + kgrp * 4];
    float4 sqb = *(const float4*)&sq[j0 + wave * 32 + 16 + kgrp * 4];
    float sqv[2][4] = { { sqa.x, sqa.y, sqa.z, sqa.w }, { sqb.x, sqb.y, sqb.z, sqb.w } };

    #pragma unroll
    for (int fi = 0; fi < 8; ++fi) {
      const int ig = rbase + fi * 16 + l15;
      #pragma unroll
      for (int fj = 0; fj < 2; ++fj) {
        #pragma unroll
        for (int r = 0; r < 4; ++r) {
          const int jg = j0 + wave * 32 + fj * 16 + kgrp * 4 + r;
          float d = fmaf(-2.0f, acc[fi][fj][r], sqv[fj][r]);
          if (jg != ig && d < bv[fi][4]) {
            INS5(bv[fi], bi[fi], d, jg);
          }
        }
      }
    }
  }

  #pragma unroll
  for (int fi = 0; fi < 8; ++fi) {
    #pragma unroll
    for (int m = 16; m <= 32; m <<= 1) {
      float ov[5]; int oi[5];
      #pragma unroll
      for (int s = 0; s < 5; ++s) {
        ov[s] = __shfl_xor(bv[fi][s], m);
        oi[s] = __shfl_xor(bi[fi][s], m);
      }
      #pragma unroll
      for (int s = 0; s < 5; ++s) {
        if (ov[s] < bv[fi][4]) { INS5(bv[fi], bi[fi], ov[s], oi[s]); }
      }
    }
  }

  __syncthreads();
  if (kgrp == 0) {
    #pragma unroll
    for (int fi = 0; fi < 8; ++fi) {
      const int row = fi * 16 + l15;
      #pragma unroll
      for (int s = 0; s < 5; ++s) {
        M[row * 80 + wave * 5 + s]      = bv[fi][s];
        M[row * 80 + 40 + wave * 5 + s] = __int_as_float(bi[fi][s]);
      }
    }
  }
  __syncthreads();
  if (tid < 128) {
    const int irow = rbase + tid;
    int* co = &cand[(size_t)irow * NC2 + blockIdx.y * NCAND];
    #pragma unroll 1
    for (int s = 0; s < NCAND; ++s) {
      float bestv = 3.0e38f; int bestid = 0x7fffffff; int bestt = 0;
      #pragma unroll 1
      for (int t = 0; t < 40; ++t) {
        float v = M[tid * 80 + t];
        int id = __float_as_int(M[tid * 80 + 40 + t]);
        if (v < bestv || (v == bestv && id < bestid)) { bestv = v; bestid = id; bestt = t; }
      }
      M[tid * 80 + bestt] = 3.0e38f;
      co[s] = bestid;
    }
  }
}

// ===================== exact fp32 rescore of 32 candidates -> top-5 =====================
__global__ __launch_bounds__(128) void rescore_kernel(
    const float* __restrict__ h, const float* __restrict__ sq,
    const int* __restrict__ cand, int* __restrict__ nbr)
{
  __shared__ float hi_s[HD];
  __shared__ float dv[NC2];
  __shared__ int   di[NC2];
  const int i = blockIdx.x;
  const int t = threadIdx.x;
  if (t < 64) *(float4*)&hi_s[t * 4] = *(const float4*)&h[(size_t)i * HD + t * 4];
  __syncthreads();
  const int c = t >> 2, q = t & 3;
  const int j = cand[(size_t)i * NC2 + c];
  float s = 0.f;
  const float4* hj  = (const float4*)&h[(size_t)j * HD + q * 64];
  const float4* hi4 = (const float4*)&hi_s[q * 64];
  #pragma unroll
  for (int u = 0; u < 16; ++u) {
    float4 a = hi4[u], b = hj[u];
    s = fmaf(a.x, b.x, s); s = fmaf(a.y, b.y, s);
    s = fmaf(a.z, b.z, s); s = fmaf(a.w, b.w, s);
  }
  s += __shfl_down(s, 1);
  s += __shfl_down(s, 2);
  if (q == 0) { dv[c] = fmaf(-2.0f, s, sq[j]); di[c] = j; }
  __syncthreads();
  if (t == 0) {
    #pragma unroll 1
    for (int sidx = 0; sidx < KNN; ++sidx) {
      float bestv = 3.0e38f; int bestid = 0x7fffffff; int bestc = 0;
      #pragma unroll 1
      for (int u = 0; u < NC2; ++u) {
        float v = dv[u]; int id = di[u];
        if (v < bestv || (v == bestv && id < bestid)) { bestv = v; bestid = id; bestc = u; }
      }
      dv[bestc] = 3.0e38f;
      nbr[i * KNN + sidx] = bestid;
    }
  }
}

// ===================== graph build =====================
__global__ void count_kernel(const int* __restrict__ nbr, int* __restrict__ cnt)
{
  int e = blockIdx.x * 256 + threadIdx.x;
  if (e < NN * KNN) atomicAdd(&cnt[nbr[e]], 1);
}

__global__ void dinv_kernel(const int* __restrict__ cnt, float* __restrict__ dinv)
{
  int i = blockIdx.x * 256 + threadIdx.x;
  if (i < NN) dinv[i] = 1.0f / sqrtf((float)(cnt[i] + KNN + 1));
}

__global__ __launch_bounds__(256) void scan_kernel(const int* __restrict__ cnt, int* __restrict__ off)
{
  __shared__ int ps[256];
  const int t = threadIdx.x;
  int s = 0;
  for (int i = 0; i < 64; ++i) s += cnt[t * 64 + i];
  ps[t] = s;
  __syncthreads();
  if (t == 0) {
    int run = 0;
    for (int q = 0; q < 256; ++q) { int v = ps[q]; ps[q] = run; run += v; }
  }
  __syncthreads();
  int base = ps[t];
  for (int i = 0; i < 64; ++i) { off[t * 64 + i] = base; base += cnt[t * 64 + i]; }
}

__global__ void fill_rev(const int* __restrict__ nbr, const int* __restrict__ off,
                         int* __restrict__ cur, int* __restrict__ rev)
{
  int e = blockIdx.x * 256 + threadIdx.x;
  if (e < NN * KNN) {
    int i = e / KNN;
    int c = nbr[e];
    int s = atomicAdd(&cur[c], 1);
    rev[off[c] + s] = i;
  }
}

// ===================== GCN aggregation (pure gather via reverse CSR) =====================
__global__ __launch_bounds__(64) void aggregate(
    const float* __restrict__ g, const int* __restrict__ nbr,
    const int* __restrict__ rev, const int* __restrict__ off, const int* __restrict__ cnt,
    const float* __restrict__ dinv, const float* __restrict__ bias,
    float* __restrict__ out, int do_relu)
{
  const int c = blockIdx.x;
  const int l = threadIdx.x;
  const float4* g4 = (const float4*)g;
  float4 v = g4[(size_t)c * (HD / 4) + l];
  float ax = v.x, ay = v.y, az = v.z, aw = v.w;
  #pragma unroll
  for (int k = 0; k < KNN; ++k) {
    int r = nbr[c * KNN + k];
    float4 u = g4[(size_t)r * (HD / 4) + l];
    ax += u.x; ay += u.y; az += u.z; aw += u.w;
  }
  const int o0 = off[c], o1 = o0 + cnt[c];
  for (int j = o0; j < o1; ++j) {
    int r = rev[j];
    float4 u = g4[(size_t)r * (HD / 4) + l];
    ax += u.x; ay += u.y; az += u.z; aw += u.w;
  }
  const float dc = dinv[c];
  float4 b = ((const float4*)bias)[l];
  float rx = ax * dc + b.x, ry = ay * dc + b.y, rz = az * dc + b.z, rw = aw * dc + b.w;
  if (do_relu) {
    rx = fmaxf(rx, 0.0f); ry = fmaxf(ry, 0.0f);
    rz = fmaxf(rz, 0.0f); rw = fmaxf(rw, 0.0f);
  }
  float4 o; o.x = rx; o.y = ry; o.z = rz; o.w = rw;
  ((float4*)out)[(size_t)c * (HD / 4) + l] = o;
}

// ===================== mean-pool + classifier =====================
__global__ __launch_bounds__(256) void colsum_kernel(const float* __restrict__ a, float* __restrict__ colsum)
{
  const int f = threadIdx.x;
  const int r0 = blockIdx.x * 64;
  float s = 0.0f;
  for (int r = 0; r < 64; ++r) s += a[(size_t)(r0 + r) * HD + f];
  atomicAdd(&colsum[f], s);
}

__global__ __launch_bounds__(256) void final_kernel(
    const float* __restrict__ colsum, const float* __restrict__ Wc,
    const float* __restrict__ bc, float* __restrict__ out)
{
  __shared__ float s0[256], s1[256];
  const int f = threadIdx.x;
  float bag = colsum[f] * (1.0f / (float)NN);
  s0[f] = bag * Wc[f * 2 + 0];
  s1[f] = bag * Wc[f * 2 + 1];
  __syncthreads();
  for (int st = 128; st; st >>= 1) {
    if (f < st) { s0[f] += s0[f + st]; s1[f] += s1[f + st]; }
    __syncthreads();
  }
  if (f == 0) { out[0] = s0[0] + bc[0]; out[1] = s1[0] + bc[1]; }
}

// ===================== launch =====================
extern "C" void kernel_launch(void* const* d_in, const int* in_sizes, int n_in,
                              void* d_out, int out_size, void* d_ws, size_t ws_size,
                              hipStream_t stream)
{
  const float* x   = (const float*)d_in[0];
  const float* Wp  = (const float*)d_in[1];
  const float* bp  = (const float*)d_in[2];
  const float* Wg1 = (const float*)d_in[3];
  const float* bg1 = (const float*)d_in[4];
  const float* Wg2 = (const float*)d_in[5];
  const float* bg2 = (const float*)d_in[6];
  const float* Wc  = (const float*)d_in[7];
  const float* bc  = (const float*)d_in[8];
  float* out = (float*)d_out;

  float* ws    = (float*)d_ws;
  float* h     = ws;                                // N*HD f32
  float* g     = ws + (size_t)NN * HD;              // N*HD f32 (written step 8)
  float* h1    = ws + 2 * (size_t)NN * HD;          // N*HD f32 (written step 9)
  float* agg2  = h;                                 // reuse
  float* sq    = ws + 3 * (size_t)NN * HD;          // N
  float* dinv  = sq + NN;                           // N
  float* colsum= dinv + NN;                         // HD
  int* nbr = (int*)(colsum + HD);                   // N*KNN
  int* cnt = nbr + NN * KNN;                        // N
  int* off = cnt + NN;                              // N
  int* cur = off + NN;                              // N
  int* rev = cur + NN;                              // N*KNN
  // bf16 hi/lo live in g / h1 regions (dead until steps 8/9, after kNN phase)
  ushort* hhi = (ushort*)g;
  ushort* hlo = (ushort*)h1;
  int* cand = (int*)(g + (size_t)NN * HD * 3 / 4);  // N*NC2 ints = 2 MB

  // 1. h = relu(x @ W_proj + b_proj)  [MFMA split-bf16 3-term]
  gemm_mfma<true, true, false><<<dim3(NN / 128, HD / 128), dim3(256), 0, stream>>>(
      x, Wp, bp, nullptr, h, NN, HD, IND);
  // 2. sq + bf16 hi/lo split (single pass over h)
  sq_split_kernel<<<dim3(NN / 4), dim3(256), 0, stream>>>(h, sq, hhi, hlo);
  // 3a. approx top-16 candidates per row per j-half (r6-measured kernel)
  dist_topk_mfma<<<dim3(NN / 128, 2), dim3(512), 0, stream>>>(hhi, hlo, sq, cand);
  // 3b. exact fp32 rescore of 32 candidates -> top-5
  rescore_kernel<<<dim3(NN), dim3(128), 0, stream>>>(h, sq, cand, nbr);
  // 4. in-degree counts
  hipMemsetAsync(cnt, 0, NN * sizeof(int), stream);
  count_kernel<<<dim3((NN * KNN) / 256), dim3(256), 0, stream>>>(nbr, cnt);
  // 5. dinv
  dinv_kernel<<<dim3(NN / 256), dim3(256), 0, stream>>>(cnt, dinv);
  // 6. CSR offsets
  scan_kernel<<<dim3(1), dim3(256), 0, stream>>>(cnt, off);
  // 7. reverse adjacency
  hipMemsetAsync(cur, 0, NN * sizeof(int), stream);
  fill_rev<<<dim3((NN * KNN) / 256), dim3(256), 0, stream>>>(nbr, off, cur, rev);
  // 8. g = (h @ W_g1) * dinv[row]  [MFMA]
  gemm_mfma<false, false, true><<<dim3(NN / 128, HD / 128), dim3(256), 0, stream>>>(
      h, Wg1, nullptr, dinv, g, NN, HD, HD);
  // 9. h1 = relu(agg(g) + b_g1)
  aggregate<<<dim3(NN), dim3(64), 0, stream>>>(g, nbr, rev, off, cnt, dinv, bg1, h1, 1);
  // 10. g = (h1 @ W_g2) * dinv[row]  [MFMA]
  gemm_mfma<false, false, true><<<dim3(NN / 128, HD / 128), dim3(256), 0, stream>>>(
      h1, Wg2, nullptr, dinv, g, NN, HD, HD);
  // 11. agg2 = agg(g) + b_g2
  aggregate<<<dim3(NN), dim3(64), 0, stream>>>(g, nbr, rev, off, cnt, dinv, bg2, agg2, 0);
  // 12/13. mean-pool + classifier
  hipMemsetAsync(colsum, 0, HD * sizeof(float), stream);
  colsum_kernel<<<dim3(NN / 64), dim3(256), 0, stream>>>(agg2, colsum);
  final_kernel<<<dim3(1), dim3(256), 0, stream>>>(colsum, Wc, bc, out);
}

// Round 18
// 900.354 us; speedup vs baseline: 2.3425x; 1.2103x over previous
//
#include <hip/hip_runtime.h>
#include <cstdint>
#include <cstddef>

#define NN 16384
#define IND 1024
#define HD 256
#define KNN 5
#define NCAND 16   // per j-half
#define NC2 32     // total candidates per row (2 halves)

typedef __attribute__((ext_vector_type(4))) float f32x4;
typedef __attribute__((ext_vector_type(8))) short bf16x8;

// ===================== fp32 -> bf16 helpers =====================
__device__ __forceinline__ ushort f2bf(float f) {
  uint32_t u = __float_as_uint(f);
  uint32_t r = (u + 0x7fffu + ((u >> 16) & 1u)) >> 16;
  return (ushort)r;
}
__device__ __forceinline__ float bf2f(ushort s) {
  return __uint_as_float(((uint32_t)s) << 16);
}

// ===================== MFMA GEMM via split-bf16 3-term (r17-measured) =====================
// C[M][N] = op(A@B [+bias] [*rowscale[m]]); A: MxK f32 row-major, B: KxN f32 row-major.
template<bool RELU, bool BIAS, bool RS>
__global__ __launch_bounds__(256) void gemm_mfma(
    const float* __restrict__ A, const float* __restrict__ B,
    const float* __restrict__ bias, const float* __restrict__ rowscale,
    float* __restrict__ C, int M, int N, int K)
{
  __shared__ ushort Ahi[128 * 40], Alo[128 * 40];   // [m][k], row 40 us (80B, padded)
  __shared__ ushort Bhi[128 * 40], Blo[128 * 40];   // [n][k] transposed
  const int tid  = threadIdx.x;
  const int wave = tid >> 6, lane = tid & 63;
  const int l15  = lane & 15, kgrp = lane >> 4;
  const int m0 = blockIdx.x * 128, n0 = blockIdx.y * 128;

  f32x4 acc[8][2];
  #pragma unroll
  for (int fi = 0; fi < 8; ++fi)
    #pragma unroll
    for (int fj = 0; fj < 2; ++fj) acc[fi][fj] = (f32x4){0.f, 0.f, 0.f, 0.f};

  const int arow = tid >> 1, ahalf = tid & 1;       // A: 2 thr/row, 16 k each
  const int bn = tid >> 1, bkh = tid & 1;           // B: 2 thr/n-col, 16 k each

  for (int kb = 0; kb < K; kb += 32) {
    #pragma unroll
    for (int c = 0; c < 4; ++c) {
      float4 v = *(const float4*)&A[(size_t)(m0 + arow) * K + kb + ahalf * 16 + c * 4];
      int o = arow * 40 + ahalf * 16 + c * 4;
      ushort h0 = f2bf(v.x), h1 = f2bf(v.y), h2 = f2bf(v.z), h3 = f2bf(v.w);
      ushort4 H; H.x = h0; H.y = h1; H.z = h2; H.w = h3;
      ushort4 L; L.x = f2bf(v.x - bf2f(h0)); L.y = f2bf(v.y - bf2f(h1));
      L.z = f2bf(v.z - bf2f(h2)); L.w = f2bf(v.w - bf2f(h3));
      *(ushort4*)&Ahi[o] = H;
      *(ushort4*)&Alo[o] = L;
    }
    #pragma unroll
    for (int i = 0; i < 16; ++i) {
      int k = bkh * 16 + i;
      float v = B[(size_t)(kb + k) * N + n0 + bn];
      ushort h = f2bf(v);
      Bhi[bn * 40 + k] = h;
      Blo[bn * 40 + k] = f2bf(v - bf2f(h));
    }
    __syncthreads();

    bf16x8 aH[2], aL[2];
    #pragma unroll
    for (int fj = 0; fj < 2; ++fj) {
      const int mr = wave * 32 + fj * 16 + l15;
      aH[fj] = *(const bf16x8*)&Ahi[mr * 40 + kgrp * 8];
      aL[fj] = *(const bf16x8*)&Alo[mr * 40 + kgrp * 8];
    }
    #pragma unroll
    for (int fi = 0; fi < 8; ++fi) {
      const int nr = fi * 16 + l15;
      bf16x8 bH = *(const bf16x8*)&Bhi[nr * 40 + kgrp * 8];
      bf16x8 bL = *(const bf16x8*)&Blo[nr * 40 + kgrp * 8];
      #pragma unroll
      for (int fj = 0; fj < 2; ++fj) {
        acc[fi][fj] = __builtin_amdgcn_mfma_f32_16x16x32_bf16(aH[fj], bH, acc[fi][fj], 0, 0, 0);
        acc[fi][fj] = __builtin_amdgcn_mfma_f32_16x16x32_bf16(aH[fj], bL, acc[fi][fj], 0, 0, 0);
        acc[fi][fj] = __builtin_amdgcn_mfma_f32_16x16x32_bf16(aL[fj], bH, acc[fi][fj], 0, 0, 0);
      }
    }
    __syncthreads();
  }

  float bv[8];
  if (BIAS) {
    #pragma unroll
    for (int fi = 0; fi < 8; ++fi) bv[fi] = bias[n0 + fi * 16 + l15];
  }
  float rsv[2][4];
  if (RS) {
    #pragma unroll
    for (int fj = 0; fj < 2; ++fj)
      #pragma unroll
      for (int r = 0; r < 4; ++r)
        rsv[fj][r] = rowscale[m0 + wave * 32 + fj * 16 + kgrp * 4 + r];
  }
  #pragma unroll
  for (int fi = 0; fi < 8; ++fi) {
    const int n = n0 + fi * 16 + l15;
    #pragma unroll
    for (int fj = 0; fj < 2; ++fj) {
      #pragma unroll
      for (int r = 0; r < 4; ++r) {
        const int m = m0 + wave * 32 + fj * 16 + kgrp * 4 + r;
        float v = acc[fi][fj][r];
        if (BIAS) v += bv[fi];
        if (RS) v *= rsv[fj][r];
        if (RELU) v = fmaxf(v, 0.0f);
        C[(size_t)m * N + n] = v;
      }
    }
  }
}

// ===================== fused row-norms + bf16 cast (one pass over h) ==========
__global__ __launch_bounds__(256) void sq_split_kernel(
    const float* __restrict__ h, float* __restrict__ sq, ushort* __restrict__ hhi)
{
  const int w = threadIdx.x >> 6, l = threadIdx.x & 63;
  const int r = blockIdx.x * 4 + w;
  float4 v = *(const float4*)&h[(size_t)r * HD + l * 4];
  float s = v.x * v.x + v.y * v.y + v.z * v.z + v.w * v.w;
  #pragma unroll
  for (int o = 32; o; o >>= 1) s += __shfl_down(s, o);
  if (l == 0) sq[r] = s;
  ushort4 H; H.x = f2bf(v.x); H.y = f2bf(v.y); H.z = f2bf(v.z); H.w = f2bf(v.w);
  *(ushort4*)&hhi[(size_t)r * HD + l * 4] = H;
}

// sorted u32-key top-5 insert (k0<k1<...<k4); key embeds index -> unique; equal
// distance-bits -> lower index = lower key (matches JAX tie-break pre-rescore).
#define INS5K(v, k) do {                                                \
    if ((k) < v[4]) {                                                   \
      if ((k) < v[0])      { v[4]=v[3];v[3]=v[2];v[2]=v[1];v[1]=v[0];v[0]=(k); } \
      else if ((k) < v[1]) { v[4]=v[3];v[3]=v[2];v[2]=v[1];v[1]=(k); }  \
      else if ((k) < v[2]) { v[4]=v[3];v[3]=v[2];v[2]=(k); }            \
      else if ((k) < v[3]) { v[4]=v[3];v[3]=(k); }                      \
      else                 { v[4]=(k); }                                \
    }                                                                   \
  } while (0)

// ===================== MFMA pairwise-distance -> top-16 candidates per j-half ==========
// r6-measured GEOMETRY (594us, FETCH 73MB: 128-row LDS panel, grid (128,2), 512 thr,
// barrier-free K-loop, exactly-co-resident grid -> phase-locked L2 sharing), now with
// the r9-validated NUMERICS: 1-term bf16 Gram (MFMA /3, j-loads /2) + packed u32 keys
// (ladder/merge VALU /2). Filter error ~0.06 << rank-5..16 spacing; exact fp32
// rescore of 32 candidates recovers the true top-5 (absmax 0.0 in r9/r10/r12/r15).
// Lane owns i = fi*16+(lane&15); j = wave*32 + fj*16 + (lane>>4)*4 + reg.
__global__ __launch_bounds__(512, 2) void dist_topk_mfma(
    const ushort* __restrict__ hhi, const float* __restrict__ sq, int* __restrict__ cand)
{
  // iHi [128][264 us] = 67584 B; merge M (uint, aliases @0): 128 x 40 x 4B = 20480 B.
  __shared__ char smem[67584];
  ushort*   iHi = (ushort*)smem;
  uint32_t* M   = (uint32_t*)smem;

  const int tid  = threadIdx.x;
  const int wave = tid >> 6, lane = tid & 63;
  const int l15  = lane & 15, kgrp = lane >> 4;
  const int rbase = blockIdx.x * 128;
  const int jbeg  = blockIdx.y * (NN / 2);

  // ---- stage i-panel (128 x 256 bf16), once: 4 threads/row, 64 us (8 x uint4) each
  {
    const int r = tid >> 2, q = tid & 3;
    const uint4* sH = (const uint4*)&hhi[(size_t)(rbase + r) * HD + q * 64];
    uint4* dH = (uint4*)&iHi[r * 264 + q * 64];
    #pragma unroll
    for (int c = 0; c < 8; ++c) dH[c] = sH[c];
  }
  __syncthreads();

  uint32_t keys[8][5];
  #pragma unroll
  for (int i = 0; i < 8; ++i)
    #pragma unroll
    for (int s = 0; s < 5; ++s) keys[i][s] = 0xFFFFFFFFu;

  for (int j0 = jbeg; j0 < jbeg + NN / 2; j0 += 256) {
    f32x4 acc[8][2];
    #pragma unroll
    for (int fi = 0; fi < 8; ++fi) {
      acc[fi][0] = (f32x4){0.f, 0.f, 0.f, 0.f};
      acc[fi][1] = (f32x4){0.f, 0.f, 0.f, 0.f};
    }

    #pragma unroll 2
    for (int kb = 0; kb < 8; ++kb) {
      bf16x8 a0 = *(const bf16x8*)&hhi[(size_t)(j0 + wave * 32 + l15) * HD + kb * 32 + kgrp * 8];
      bf16x8 a1 = *(const bf16x8*)&hhi[(size_t)(j0 + wave * 32 + 16 + l15) * HD + kb * 32 + kgrp * 8];
      #pragma unroll
      for (int fi = 0; fi < 8; ++fi) {
        bf16x8 b = *(const bf16x8*)&iHi[(fi * 16 + l15) * 264 + kb * 32 + kgrp * 8];
        acc[fi][0] = __builtin_amdgcn_mfma_f32_16x16x32_bf16(a0, b, acc[fi][0], 0, 0, 0);
        acc[fi][1] = __builtin_amdgcn_mfma_f32_16x16x32_bf16(a1, b, acc[fi][1], 0, 0, 0);
      }
    }

    float4 sqa = *(const float4*)&sq[j0 + wave * 32 + kgrp * 4];
    float4 sqb = *(const float4*)&sq[j0 + wave * 32 + 16 + kgrp * 4];
    float sqv[2][4] = { { sqa.x, sqa.y, sqa.z, sqa.w }, { sqb.x, sqb.y, sqb.z, sqb.w } };

    // self-pair only possible in the one 256-chunk containing this block's 128 i-rows
    const bool selfchunk = ((rbase >> 8) == (j0 >> 8));

#define EPI_SLOT(fi, fj, r, CHECK)                                              \
    {                                                                           \
      const int jg = j0 + wave * 32 + (fj) * 16 + kgrp * 4 + (r);               \
      float d = fmaf(-2.0f, acc[fi][fj][r], sqv[fj][r]);                        \
      uint32_t u = __float_as_uint(d);                                          \
      u ^= (uint32_t)((int32_t)u >> 31) | 0x80000000u;                          \
      uint32_t key = (u & 0xFFFFC000u) | (uint32_t)jg;                          \
      if (!(CHECK) || jg != (rbase + (fi) * 16 + l15)) INS5K(keys[fi], key);    \
    }

    if (selfchunk) {
      #pragma unroll
      for (int fi = 0; fi < 8; ++fi)
        #pragma unroll
        for (int fj = 0; fj < 2; ++fj)
          #pragma unroll
          for (int r = 0; r < 4; ++r) EPI_SLOT(fi, fj, r, true)
    } else {
      #pragma unroll
      for (int fi = 0; fi < 8; ++fi)
        #pragma unroll
        for (int fj = 0; fj < 2; ++fj)
          #pragma unroll
          for (int r = 0; r < 4; ++r) EPI_SLOT(fi, fj, r, false)
    }
#undef EPI_SLOT
  }

  // ---- merge 4 kgrp partials within each wave (shuffle butterfly, lane bits 4,5)
  #pragma unroll
  for (int fi = 0; fi < 8; ++fi) {
    #pragma unroll
    for (int m = 16; m <= 32; m <<= 1) {
      uint32_t ok[5];
      #pragma unroll
      for (int s = 0; s < 5; ++s)
        ok[s] = (uint32_t)__shfl_xor((int)keys[fi][s], m);
      #pragma unroll
      for (int s = 0; s < 5; ++s) INS5K(keys[fi], ok[s]);
    }
  }

  // ---- 8 wave-partials x 5 keys per row -> LDS -> top-16 candidates for this half
  __syncthreads();   // i-panel reads done; reuse LDS as M
  if (kgrp == 0) {
    #pragma unroll
    for (int fi = 0; fi < 8; ++fi) {
      const int row = fi * 16 + l15;
      #pragma unroll
      for (int s = 0; s < 5; ++s)
        M[row * 40 + wave * 5 + s] = keys[fi][s];
    }
  }
  __syncthreads();
  if (tid < 128) {
    const int irow = rbase + tid;
    int* co = &cand[(size_t)irow * NC2 + blockIdx.y * NCAND];
    #pragma unroll 1
    for (int s = 0; s < NCAND; ++s) {
      uint32_t best = 0xFFFFFFFFu; int bestt = 0;
      #pragma unroll 1
      for (int t = 0; t < 40; ++t) {
        uint32_t v = M[tid * 40 + t];
        if (v < best) { best = v; bestt = t; }
      }
      M[tid * 40 + bestt] = 0xFFFFFFFFu;
      co[s] = (int)(best & 0x3FFFu);
    }
  }
}

// ===================== exact fp32 rescore of 32 candidates -> top-5 =====================
__global__ __launch_bounds__(128) void rescore_kernel(
    const float* __restrict__ h, const float* __restrict__ sq,
    const int* __restrict__ cand, int* __restrict__ nbr)
{
  __shared__ float hi_s[HD];
  __shared__ float dv[NC2];
  __shared__ int   di[NC2];
  const int i = blockIdx.x;
  const int t = threadIdx.x;
  if (t < 64) *(float4*)&hi_s[t * 4] = *(const float4*)&h[(size_t)i * HD + t * 4];
  __syncthreads();
  const int c = t >> 2, q = t & 3;
  const int j = cand[(size_t)i * NC2 + c];
  float s = 0.f;
  const float4* hj  = (const float4*)&h[(size_t)j * HD + q * 64];
  const float4* hi4 = (const float4*)&hi_s[q * 64];
  #pragma unroll
  for (int u = 0; u < 16; ++u) {
    float4 a = hi4[u], b = hj[u];
    s = fmaf(a.x, b.x, s); s = fmaf(a.y, b.y, s);
    s = fmaf(a.z, b.z, s); s = fmaf(a.w, b.w, s);
  }
  s += __shfl_down(s, 1);
  s += __shfl_down(s, 2);
  if (q == 0) { dv[c] = fmaf(-2.0f, s, sq[j]); di[c] = j; }
  __syncthreads();
  if (t == 0) {
    #pragma unroll 1
    for (int sidx = 0; sidx < KNN; ++sidx) {
      float bestv = 3.0e38f; int bestid = 0x7fffffff; int bestc = 0;
      #pragma unroll 1
      for (int u = 0; u < NC2; ++u) {
        float v = dv[u]; int id = di[u];
        if (v < bestv || (v == bestv && id < bestid)) { bestv = v; bestid = id; bestc = u; }
      }
      dv[bestc] = 3.0e38f;
      nbr[i * KNN + sidx] = bestid;
    }
  }
}

// ===================== graph build =====================
__global__ void count_kernel(const int* __restrict__ nbr, int* __restrict__ cnt)
{
  int e = blockIdx.x * 256 + threadIdx.x;
  if (e < NN * KNN) atomicAdd(&cnt[nbr[e]], 1);
}

__global__ void dinv_kernel(const int* __restrict__ cnt, float* __restrict__ dinv)
{
  int i = blockIdx.x * 256 + threadIdx.x;
  if (i < NN) dinv[i] = 1.0f / sqrtf((float)(cnt[i] + KNN + 1));
}

__global__ __launch_bounds__(256) void scan_kernel(const int* __restrict__ cnt, int* __restrict__ off)
{
  __shared__ int ps[256];
  const int t = threadIdx.x;
  int s = 0;
  for (int i = 0; i < 64; ++i) s += cnt[t * 64 + i];
  ps[t] = s;
  __syncthreads();
  if (t == 0) {
    int run = 0;
    for (int q = 0; q < 256; ++q) { int v = ps[q]; ps[q] = run; run += v; }
  }
  __syncthreads();
  int base = ps[t];
  for (int i = 0; i < 64; ++i) { off[t * 64 + i] = base; base += cnt[t * 64 + i]; }
}

__global__ void fill_rev(const int* __restrict__ nbr, const int* __restrict__ off,
                         int* __restrict__ cur, int* __restrict__ rev)
{
  int e = blockIdx.x * 256 + threadIdx.x;
  if (e < NN * KNN) {
    int i = e / KNN;
    int c = nbr[e];
    int s = atomicAdd(&cur[c], 1);
    rev[off[c] + s] = i;
  }
}

// ===================== GCN aggregation (pure gather via reverse CSR) =====================
__global__ __launch_bounds__(64) void aggregate(
    const float* __restrict__ g, const int* __restrict__ nbr,
    const int* __restrict__ rev, const int* __restrict__ off, const int* __restrict__ cnt,
    const float* __restrict__ dinv, const float* __restrict__ bias,
    float* __restrict__ out, int do_relu)
{
  const int c = blockIdx.x;
  const int l = threadIdx.x;
  const float4* g4 = (const float4*)g;
  float4 v = g4[(size_t)c * (HD / 4) + l];
  float ax = v.x, ay = v.y, az = v.z, aw = v.w;
  #pragma unroll
  for (int k = 0; k < KNN; ++k) {
    int r = nbr[c * KNN + k];
    float4 u = g4[(size_t)r * (HD / 4) + l];
    ax += u.x; ay += u.y; az += u.z; aw += u.w;
  }
  const int o0 = off[c], o1 = o0 + cnt[c];
  for (int j = o0; j < o1; ++j) {
    int r = rev[j];
    float4 u = g4[(size_t)r * (HD / 4) + l];
    ax += u.x; ay += u.y; az += u.z; aw += u.w;
  }
  const float dc = dinv[c];
  float4 b = ((const float4*)bias)[l];
  float rx = ax * dc + b.x, ry = ay * dc + b.y, rz = az * dc + b.z, rw = aw * dc + b.w;
  if (do_relu) {
    rx = fmaxf(rx, 0.0f); ry = fmaxf(ry, 0.0f);
    rz = fmaxf(rz, 0.0f); rw = fmaxf(rw, 0.0f);
  }
  float4 o; o.x = rx; o.y = ry; o.z = rz; o.w = rw;
  ((float4*)out)[(size_t)c * (HD / 4) + l] = o;
}

// ===================== mean-pool + classifier =====================
__global__ __launch_bounds__(256) void colsum_kernel(const float* __restrict__ a, float* __restrict__ colsum)
{
  const int f = threadIdx.x;
  const int r0 = blockIdx.x * 64;
  float s = 0.0f;
  for (int r = 0; r < 64; ++r) s += a[(size_t)(r0 + r) * HD + f];
  atomicAdd(&colsum[f], s);
}

__global__ __launch_bounds__(256) void final_kernel(
    const float* __restrict__ colsum, const float* __restrict__ Wc,
    const float* __restrict__ bc, float* __restrict__ out)
{
  __shared__ float s0[256], s1[256];
  const int f = threadIdx.x;
  float bag = colsum[f] * (1.0f / (float)NN);
  s0[f] = bag * Wc[f * 2 + 0];
  s1[f] = bag * Wc[f * 2 + 1];
  __syncthreads();
  for (int st = 128; st; st >>= 1) {
    if (f < st) { s0[f] += s0[f + st]; s1[f] += s1[f + st]; }
    __syncthreads();
  }
  if (f == 0) { out[0] = s0[0] + bc[0]; out[1] = s1[0] + bc[1]; }
}

// ===================== launch =====================
extern "C" void kernel_launch(void* const* d_in, const int* in_sizes, int n_in,
                              void* d_out, int out_size, void* d_ws, size_t ws_size,
                              hipStream_t stream)
{
  const float* x   = (const float*)d_in[0];
  const float* Wp  = (const float*)d_in[1];
  const float* bp  = (const float*)d_in[2];
  const float* Wg1 = (const float*)d_in[3];
  const float* bg1 = (const float*)d_in[4];
  const float* Wg2 = (const float*)d_in[5];
  const float* bg2 = (const float*)d_in[6];
  const float* Wc  = (const float*)d_in[7];
  const float* bc  = (const float*)d_in[8];
  float* out = (float*)d_out;

  float* ws    = (float*)d_ws;
  float* h     = ws;                                // N*HD f32
  float* g     = ws + (size_t)NN * HD;              // N*HD f32 (written step 8)
  float* h1    = ws + 2 * (size_t)NN * HD;          // N*HD f32 (written step 9)
  float* agg2  = h;                                 // reuse
  float* sq    = ws + 3 * (size_t)NN * HD;          // N
  float* dinv  = sq + NN;                           // N
  float* colsum= dinv + NN;                         // HD
  int* nbr = (int*)(colsum + HD);                   // N*KNN
  int* cnt = nbr + NN * KNN;                        // N
  int* off = cnt + NN;                              // N
  int* cur = off + NN;                              // N
  int* rev = cur + NN;                              // N*KNN
  // bf16 hi lives in g region (dead until step 8, after kNN phase)
  ushort* hhi = (ushort*)g;
  int* cand = (int*)(g + (size_t)NN * HD * 3 / 4);  // N*NC2 ints = 2 MB

  // 1. h = relu(x @ W_proj + b_proj)  [MFMA split-bf16 3-term]
  gemm_mfma<true, true, false><<<dim3(NN / 128, HD / 128), dim3(256), 0, stream>>>(
      x, Wp, bp, nullptr, h, NN, HD, IND);
  // 2. sq + bf16 cast (single pass over h)
  sq_split_kernel<<<dim3(NN / 4), dim3(256), 0, stream>>>(h, sq, hhi);
  // 3a. approx top-16 per j-half (r6 geometry + 1-term Gram + u32 keys)
  dist_topk_mfma<<<dim3(NN / 128, 2), dim3(512), 0, stream>>>(hhi, sq, cand);
  // 3b. exact fp32 rescore of 32 candidates -> top-5
  rescore_kernel<<<dim3(NN), dim3(128), 0, stream>>>(h, sq, cand, nbr);
  // 4. in-degree counts
  hipMemsetAsync(cnt, 0, NN * sizeof(int), stream);
  count_kernel<<<dim3((NN * KNN) / 256), dim3(256), 0, stream>>>(nbr, cnt);
  // 5. dinv
  dinv_kernel<<<dim3(NN / 256), dim3(256), 0, stream>>>(cnt, dinv);
  // 6. CSR offsets
  scan_kernel<<<dim3(1), dim3(256), 0, stream>>>(cnt, off);
  // 7. reverse adjacency
  hipMemsetAsync(cur, 0, NN * sizeof(int), stream);
  fill_rev<<<dim3((NN * KNN) / 256), dim3(256), 0, stream>>>(nbr, off, cur, rev);
  // 8. g = (h @ W_g1) * dinv[row]  [MFMA]
  gemm_mfma<false, false, true><<<dim3(NN / 128, HD / 128), dim3(256), 0, stream>>>(
      h, Wg1, nullptr, dinv, g, NN, HD, HD);
  // 9. h1 = relu(agg(g) + b_g1)
  aggregate<<<dim3(NN), dim3(64), 0, stream>>>(g, nbr, rev, off, cnt, dinv, bg1, h1, 1);
  // 10. g = (h1 @ W_g2) * dinv[row]  [MFMA]
  gemm_mfma<false, false, true><<<dim3(NN / 128, HD / 128), dim3(256), 0, stream>>>(
      h1, Wg2, nullptr, dinv, g, NN, HD, HD);
  // 11. agg2 = agg(g) + b_g2
  aggregate<<<dim3(NN), dim3(64), 0, stream>>>(g, nbr, rev, off, cnt, dinv, bg2, agg2, 0);
  // 12/13. mean-pool + classifier
  hipMemsetAsync(colsum, 0, HD * sizeof(float), stream);
  colsum_kernel<<<dim3(NN / 64), dim3(256), 0, stream>>>(agg2, colsum);
  final_kernel<<<dim3(1), dim3(256), 0, stream>>>(colsum, Wc, bc, out);
}